// Round 14
// baseline (297.578 us; speedup 1.0000x reference)
//
#include <hip/hip_runtime.h>

#define B_ 2
#define C_ 256
#define IC_ 128
#define N_ 4096
#define KSEL 2048
#define SP 4104   // S slab pitch (f16): 4096 + 8 pad, rows 16B-aligned

// workspace offsets (floats) — ~25 MB total
#define OFF_GC    0u          // gc f32 [B][N][IC]
#define OFF_Y     1048576u    // y  f32 [B][C][N]
#define OFF_MEAN  3145728u
#define OFF_RSIG  3145984u
#define OFF_CNT   3146240u
#define OFF_LIST  3146304u    // int[B*N]
#define OFF_THB   3154496u    // theta f16 [B][N][IC]
#define OFF_PHB   3678784u    // phi   f16 [B][N][IC]
#define OFF_GWT   4203072u    // gW^T  f16 [B][IC][N]
#define OFF_XTH   4727360u    // x^T   f16 [B][N][C]
#define OFF_WALL  5775936u    // {Wth,Weff,Wph} f16 [384][256]
#define OFF_BALL  5825088u    // f32 [384]

typedef __attribute__((ext_vector_type(8))) _Float16 f16x8;
typedef __attribute__((ext_vector_type(4))) float f32x4;

__device__ __forceinline__ unsigned short f2h(float f) {
    union { _Float16 h; unsigned short u; } cv;
    cv.h = (_Float16)f;
    return cv.u;
}
__device__ __forceinline__ float h2f(unsigned short u) {
    union { unsigned short u; _Float16 h; } cv;
    cv.u = u;
    return (float)cv.h;
}

// ---------------------------------------------------------------------------
// prep: fused {xT transpose (0..511), W pack + Weff (512..895),
//              compaction (896..897), gc zeroing (898..1409)}
// ---------------------------------------------------------------------------
__global__ __launch_bounds__(256) void prep_kernel(
    const float* __restrict__ x, unsigned short* __restrict__ xTH,
    const float* __restrict__ Wth, const float* __restrict__ bth,
    const float* __restrict__ Wg,  const float* __restrict__ bg,
    const float* __restrict__ Wgcn,
    const float* __restrict__ Wph, const float* __restrict__ bph,
    unsigned short* __restrict__ WallH, float* __restrict__ ball,
    const float* __restrict__ hard_map, int* __restrict__ cnt,
    int* __restrict__ list, float* __restrict__ gc)
{
    __shared__ float Xs[64][65];
    __shared__ int wsum[4];
    const int bid = blockIdx.x;
    const int t = threadIdx.x;

    if (bid < 512) {
        const int n0 = (bid & 63) * 64;
        const int c0 = ((bid >> 6) & 3) * 64;
        const int b  = bid >> 8;
#pragma unroll
        for (int s = 0; s < 4; ++s) {
            int e4 = t + 256 * s;
            int cc = e4 >> 4, c4 = e4 & 15;
            float4 v = *(const float4*)&x[((size_t)b * C_ + c0 + cc) * N_ + n0 + c4 * 4];
            Xs[cc][c4 * 4 + 0] = v.x; Xs[cc][c4 * 4 + 1] = v.y;
            Xs[cc][c4 * 4 + 2] = v.z; Xs[cc][c4 * 4 + 3] = v.w;
        }
        __syncthreads();
#pragma unroll
        for (int s = 0; s < 4; ++s) {
            int e = t + 256 * s;
            int nn = e >> 4, c4 = e & 15;
            ushort4 h;
            h.x = f2h(Xs[c4 * 4 + 0][nn]);
            h.y = f2h(Xs[c4 * 4 + 1][nn]);
            h.z = f2h(Xs[c4 * 4 + 2][nn]);
            h.w = f2h(Xs[c4 * 4 + 3][nn]);
            *(ushort4*)&xTH[((size_t)b * N_ + n0 + nn) * C_ + c0 + c4 * 4] = h;
        }
    } else if (bid < 896) {
        const int o = bid - 512;
        const int c = t;
        const int oo = o & 127;
        float wv, bv;
        if (o < 128) {
            wv = Wth[oo * C_ + c];
            bv = bth[oo];
        } else if (o < 256) {
            float acc = 0.f;
            for (int i = 0; i < IC_; ++i)
                acc = fmaf(Wgcn[i * IC_ + oo], Wg[i * C_ + c], acc);
            wv = acc;
            float bacc = 0.f;
            for (int i = 0; i < IC_; ++i)
                bacc = fmaf(Wgcn[i * IC_ + oo], bg[i], bacc);
            bv = bacc;
        } else {
            wv = Wph[oo * C_ + c];
            bv = bph[oo];
        }
        WallH[o * C_ + c] = f2h(wv);
        if (c == 0) ball[o] = bv;
    } else if (bid < 898) {
        const int b = bid - 896;
        const int lane = t & 63, wid = t >> 6;
        const float* hm = hard_map + (size_t)b * N_;
        int flags[16];
        int c = 0;
#pragma unroll
        for (int q = 0; q < 4; ++q) {
            float4 v = *(const float4*)&hm[t * 16 + q * 4];
            flags[q * 4 + 0] = v.x > 0.5f;
            flags[q * 4 + 1] = v.y > 0.5f;
            flags[q * 4 + 2] = v.z > 0.5f;
            flags[q * 4 + 3] = v.w > 0.5f;
            c += flags[q * 4] + flags[q * 4 + 1] + flags[q * 4 + 2] + flags[q * 4 + 3];
        }
        int xv = c;
#pragma unroll
        for (int off = 1; off < 64; off <<= 1) {
            int y = __shfl_up(xv, off);
            if (lane >= off) xv += y;
        }
        if (lane == 63) wsum[wid] = xv;
        __syncthreads();
        int base = 0;
        for (int ww = 0; ww < wid; ++ww) base += wsum[ww];
        int pos = base + xv - c;
        int* lst = list + b * N_;
#pragma unroll
        for (int e = 0; e < 16; ++e) {
            int n = t * 16 + e;
            if (flags[e]) lst[pos++] = n;
        }
        if (t == 0) {
            int tot = 0;
#pragma unroll
            for (int ww = 0; ww < 4; ++ww) tot += wsum[ww];
            cnt[b] = tot;
        }
    } else {
        // zero gc: 512 blocks x 2048 floats
        float* g = gc + (size_t)(bid - 898) * 2048;
        float4 z4 = make_float4(0.f, 0.f, 0.f, 0.f);
        *(float4*)&g[t * 4] = z4;
        *(float4*)&g[1024 + t * 4] = z4;
    }
}

// ---------------------------------------------------------------------------
// proj (MFMA f16): out[o][n] = WallH[pj-chunk] . xT, K=256.
// grid (N/128, 3, B)
// ---------------------------------------------------------------------------
__global__ __launch_bounds__(256) void proj_kernel(
    const unsigned short* __restrict__ xTH,
    const unsigned short* __restrict__ WallH, const float* __restrict__ ball,
    unsigned short* __restrict__ thetaH, unsigned short* __restrict__ gWTH,
    unsigned short* __restrict__ phiH)
{
    __shared__ unsigned short Xt[128][72];
    __shared__ unsigned short Wt[128][72];
    const int n0 = blockIdx.x * 128;
    const int pj = blockIdx.y;
    const int b  = blockIdx.z;
    const int t = threadIdx.x, w = t >> 6, lane = t & 63;
    const int lrow = lane & 15, lk = (lane >> 4) * 8;
    const int wA = (w >> 1) * 64, wB = (w & 1) * 64;

    f32x4 acc[4][4];
#pragma unroll
    for (int u = 0; u < 4; ++u)
#pragma unroll
        for (int v = 0; v < 4; ++v) acc[u][v] = (f32x4)(0.f);

    for (int kc = 0; kc < C_; kc += 64) {
        __syncthreads();
#pragma unroll
        for (int s = 0; s < 4; ++s) {
            int e4 = t + 256 * s;
            int r = e4 >> 3, k8 = e4 & 7;
            *(float4*)&Xt[r][k8 * 8] =
                *(const float4*)&xTH[((size_t)b * N_ + n0 + r) * C_ + kc + k8 * 8];
        }
#pragma unroll
        for (int s = 0; s < 4; ++s) {
            int e4 = t + 256 * s;
            int r = e4 >> 3, k8 = e4 & 7;
            *(float4*)&Wt[r][k8 * 8] =
                *(const float4*)&WallH[(size_t)(pj * 128 + r) * C_ + kc + k8 * 8];
        }
        __syncthreads();

#pragma unroll
        for (int kstep = 0; kstep < 2; ++kstep) {
            const int kk = kstep * 32 + lk;
            f16x8 af[4], bf[4];
            if (pj != 1) {
#pragma unroll
                for (int u = 0; u < 4; ++u)
                    af[u] = *(const f16x8*)&Wt[wA + u * 16 + lrow][kk];
#pragma unroll
                for (int v = 0; v < 4; ++v)
                    bf[v] = *(const f16x8*)&Xt[wB + v * 16 + lrow][kk];
            } else {
#pragma unroll
                for (int u = 0; u < 4; ++u)
                    af[u] = *(const f16x8*)&Xt[wA + u * 16 + lrow][kk];
#pragma unroll
                for (int v = 0; v < 4; ++v)
                    bf[v] = *(const f16x8*)&Wt[wB + v * 16 + lrow][kk];
            }
#pragma unroll
            for (int u = 0; u < 4; ++u)
#pragma unroll
                for (int v = 0; v < 4; ++v)
                    acc[u][v] = __builtin_amdgcn_mfma_f32_16x16x32_f16(
                        af[u], bf[v], acc[u][v], 0, 0, 0);
        }
    }

    const int crow = (lane >> 4) * 4;
    if (pj != 1) {
        unsigned short* dst = (pj == 0) ? thetaH : phiH;
        const int bb2 = (pj == 0) ? 0 : 256;
#pragma unroll
        for (int u = 0; u < 4; ++u) {
            const int ob = wA + u * 16 + crow;
            float b0 = ball[bb2 + ob + 0], b1 = ball[bb2 + ob + 1];
            float b2 = ball[bb2 + ob + 2], b3 = ball[bb2 + ob + 3];
#pragma unroll
            for (int v = 0; v < 4; ++v) {
                const int n = n0 + wB + v * 16 + lrow;
                ushort4 h;
                h.x = f2h(acc[u][v][0] + b0);
                h.y = f2h(acc[u][v][1] + b1);
                h.z = f2h(acc[u][v][2] + b2);
                h.w = f2h(acc[u][v][3] + b3);
                *(ushort4*)&dst[((size_t)b * N_ + n) * IC_ + ob] = h;
            }
        }
    } else {
#pragma unroll
        for (int v = 0; v < 4; ++v) {
            const int o = wB + v * 16 + lrow;
            const float bo = ball[128 + o];
#pragma unroll
            for (int u = 0; u < 4; ++u) {
                const int nb = n0 + wA + u * 16 + crow;
                ushort4 h;
                h.x = f2h(acc[u][v][0] + bo);
                h.y = f2h(acc[u][v][1] + bo);
                h.z = f2h(acc[u][v][2] + bo);
                h.w = f2h(acc[u][v][3] + bo);
                *(ushort4*)&gWTH[((size_t)b * IC_ + o) * N_ + nb] = h;
            }
        }
    }
}

// ---------------------------------------------------------------------------
// attn: fused score + exact top-k select + softmax + PV + scatter.
// Block = 16 hard rows, 512 threads (8 waves). S lives in LDS only.
// grid (N/16, B)
// ---------------------------------------------------------------------------
__global__ __launch_bounds__(512, 1) void attn_kernel(
    const unsigned short* __restrict__ thetaH,
    const unsigned short* __restrict__ phiH,
    const unsigned short* __restrict__ gWTH,
    const int* __restrict__ cnt, const int* __restrict__ list,
    float* __restrict__ gc)
{
    __shared__ unsigned short S[16][SP];       // 131,328 B
    __shared__ unsigned short Th[16][136];     //   4,352 B
    __shared__ unsigned int sHist[8][256];     //   8,192 B
    __shared__ unsigned int sWsum[4];
    __shared__ float sRedM[8], sRedZ[8], sRedS[8];
    __shared__ unsigned int sPrefix, sRemain;
    __shared__ int sIdx[16];

    const int b = blockIdx.y;
    const int count = cnt[b];
    const int r0 = blockIdx.x * 16;
    if (r0 >= count) return;
    const int t = threadIdx.x;
    const int w = t >> 6, lane = t & 63;
    const int lrow = lane & 15, lk4 = lane >> 4, lk = lk4 * 8;

    if (t < 16) {
        int gr = r0 + t;
        sIdx[t] = (gr < count) ? list[b * N_ + gr] : -1;
    }
    __syncthreads();
    if (t < 256) {
        int r = t >> 4, k8 = t & 15;
        int gr = sIdx[r];
        float4 v = make_float4(0.f, 0.f, 0.f, 0.f);
        if (gr >= 0)
            v = *(const float4*)&thetaH[((size_t)b * N_ + gr) * IC_ + k8 * 8];
        *(float4*)&Th[r][k8 * 8] = v;
    }
    __syncthreads();

    // theta B-fragments, loaded once
    f16x8 bt[4];
#pragma unroll
    for (int ks = 0; ks < 4; ++ks)
        bt[ks] = *(const f16x8*)&Th[lrow][ks * 32 + lk];

    // ---- score: wave w computes m in [w*512, w*512+512) ----
    const unsigned short* phiB = phiH + (size_t)b * N_ * IC_;
    const int mW = w * 512;
    for (int mt = 0; mt < 32; mt += 2) {
        const int mb0 = mW + mt * 16, mb1 = mb0 + 16;
        f16x8 a0[4], a1[4];
#pragma unroll
        for (int ks = 0; ks < 4; ++ks) {
            a0[ks] = *(const f16x8*)&phiB[(size_t)(mb0 + lrow) * IC_ + ks * 32 + lk];
            a1[ks] = *(const f16x8*)&phiB[(size_t)(mb1 + lrow) * IC_ + ks * 32 + lk];
        }
        f32x4 c0 = (f32x4)(0.f), c1 = (f32x4)(0.f);
#pragma unroll
        for (int ks = 0; ks < 4; ++ks) {
            c0 = __builtin_amdgcn_mfma_f32_16x16x32_f16(a0[ks], bt[ks], c0, 0, 0, 0);
            c1 = __builtin_amdgcn_mfma_f32_16x16x32_f16(a1[ks], bt[ks], c1, 0, 0, 0);
        }
        ushort4 h0, h1;
        h0.x = f2h(c0[0]); h0.y = f2h(c0[1]); h0.z = f2h(c0[2]); h0.w = f2h(c0[3]);
        h1.x = f2h(c1[0]); h1.y = f2h(c1[1]); h1.z = f2h(c1[2]); h1.w = f2h(c1[3]);
        *(ushort4*)&S[lrow][mb0 + lk4 * 4] = h0;
        *(ushort4*)&S[lrow][mb1 + lk4 * 4] = h1;
    }
    __syncthreads();

    // ---- select: per row, all 512 threads, 8 elems each ----
    for (int rr = 0; rr < 16; ++rr) {
        uint4 rv = *(const uint4*)&S[rr][t * 8];
        float sv[8];
        unsigned int mu[8];
        const unsigned int* pu = (const unsigned int*)&rv;
#pragma unroll
        for (int dw = 0; dw < 4; ++dw) {
            unsigned int u = pu[dw];
            unsigned short hh0 = (unsigned short)(u & 0xffffu);
            unsigned short hh1 = (unsigned short)(u >> 16);
            sv[dw * 2]     = h2f(hh0);
            sv[dw * 2 + 1] = h2f(hh1);
            mu[dw * 2]     = (hh0 & 0x8000u) ? (unsigned)((~hh0) & 0xffffu)
                                             : (unsigned)(hh0 | 0x8000u);
            mu[dw * 2 + 1] = (hh1 & 0x8000u) ? (unsigned)((~hh1) & 0xffffu)
                                             : (unsigned)(hh1 | 0x8000u);
        }

        float m = -3.4e38f;
#pragma unroll
        for (int e = 0; e < 8; ++e) m = fmaxf(m, sv[e]);
#pragma unroll
        for (int off = 32; off > 0; off >>= 1) m = fmaxf(m, __shfl_xor(m, off));
        if (lane == 0) sRedM[w] = m;
        __syncthreads();
        m = sRedM[0];
#pragma unroll
        for (int ww = 1; ww < 8; ++ww) m = fmaxf(m, sRedM[ww]);

        unsigned int prefix = 0u, remain = KSEL;
        for (int d = 1; d >= 0; --d) {
            __syncthreads();
#pragma unroll
            for (int q = 0; q < 4; ++q)
                ((unsigned int*)sHist)[t + 512 * q] = 0u;
            __syncthreads();
#pragma unroll
            for (int e = 0; e < 8; ++e)
                if ((mu[e] >> (8 * (d + 1))) == prefix)
                    atomicAdd(&sHist[w][(mu[e] >> (8 * d)) & 255u], 1u);
            __syncthreads();
            unsigned int x = 0, own = 0;
            if (t < 256) {
#pragma unroll
                for (int ww = 0; ww < 8; ++ww) x += sHist[ww][t];
                own = x;
#pragma unroll
                for (int off = 1; off < 64; off <<= 1) {
                    unsigned int yv = __shfl_down(x, off);
                    if (lane + off < 64) x += yv;
                }
                if (lane == 0) sWsum[w] = x;
            }
            __syncthreads();
            if (t < 256) {
                for (int ww = w + 1; ww < 4; ++ww) x += sWsum[ww];
                unsigned int nxt = x - own;
                if (x >= remain && nxt < remain) {
                    sPrefix = (prefix << 8) | (unsigned)t;
                    sRemain = remain - nxt;
                }
            }
            __syncthreads();
            prefix = sPrefix;
            remain = sRemain;
        }
        const unsigned int tu = prefix;

        float z = 0.f, ssel = 0.f;
#pragma unroll
        for (int e = 0; e < 8; ++e) {
            float ex = expf(sv[e] - m);
            z += ex;
            if (mu[e] >= tu) ssel += ex;
        }
#pragma unroll
        for (int off = 32; off > 0; off >>= 1) {
            z    += __shfl_xor(z, off);
            ssel += __shfl_xor(ssel, off);
        }
        if (lane == 0) { sRedZ[w] = z; sRedS[w] = ssel; }
        __syncthreads();
        float zt = 0.f, st = 0.f;
#pragma unroll
        for (int ww = 0; ww < 8; ++ww) { zt += sRedZ[ww]; st += sRedS[ww]; }
        const float inv = 1.f / (st + 1e-6f * zt);

        uint4 pvv;
        unsigned int* po = (unsigned int*)&pvv;
#pragma unroll
        for (int dw = 0; dw < 4; ++dw) {
            unsigned int p0 = (mu[dw * 2] >= tu)
                ? (unsigned)f2h(expf(sv[dw * 2] - m) * inv) : 0u;
            unsigned int p1 = (mu[dw * 2 + 1] >= tu)
                ? (unsigned)f2h(expf(sv[dw * 2 + 1] - m) * inv) : 0u;
            po[dw] = p0 | (p1 << 16);
        }
        *(uint4*)&S[rr][t * 8] = pvv;
        __syncthreads();
    }

    // ---- PV: wave w -> i-tile [w*16, w*16+16), K = 4096, 4 ILP chains ----
    const unsigned short* gWB = gWTH + ((size_t)b * IC_ + w * 16 + lrow) * N_;
    f32x4 pa0 = (f32x4)(0.f), pa1 = (f32x4)(0.f);
    f32x4 pa2 = (f32x4)(0.f), pa3 = (f32x4)(0.f);
    for (int j = 0; j < N_; j += 128) {
        f16x8 g0 = *(const f16x8*)&gWB[j + lk];
        f16x8 g1 = *(const f16x8*)&gWB[j + 32 + lk];
        f16x8 g2 = *(const f16x8*)&gWB[j + 64 + lk];
        f16x8 g3 = *(const f16x8*)&gWB[j + 96 + lk];
        f16x8 p0 = *(const f16x8*)&S[lrow][j + lk];
        f16x8 p1 = *(const f16x8*)&S[lrow][j + 32 + lk];
        f16x8 p2 = *(const f16x8*)&S[lrow][j + 64 + lk];
        f16x8 p3 = *(const f16x8*)&S[lrow][j + 96 + lk];
        pa0 = __builtin_amdgcn_mfma_f32_16x16x32_f16(g0, p0, pa0, 0, 0, 0);
        pa1 = __builtin_amdgcn_mfma_f32_16x16x32_f16(g1, p1, pa1, 0, 0, 0);
        pa2 = __builtin_amdgcn_mfma_f32_16x16x32_f16(g2, p2, pa2, 0, 0, 0);
        pa3 = __builtin_amdgcn_mfma_f32_16x16x32_f16(g3, p3, pa3, 0, 0, 0);
    }
    f32x4 tot = pa0 + pa1;
    tot = tot + pa2;
    tot = tot + pa3;

    const int n = sIdx[lrow];
    if (n >= 0) {
        float4 o;
        o.x = fmaxf(tot[0], 0.f);
        o.y = fmaxf(tot[1], 0.f);
        o.z = fmaxf(tot[2], 0.f);
        o.w = fmaxf(tot[3], 0.f);
        *(float4*)&gc[((size_t)b * N_ + n) * IC_ + w * 16 + lk4 * 4] = o;
    }
}

// ---------------------------------------------------------------------------
// y[b,c,n] = Wout[c,:] . gc[b,n,:] + bout[c].  64c x 64n tiles.
// ---------------------------------------------------------------------------
__global__ __launch_bounds__(256) void y_kernel(
    const float* __restrict__ gc, const float* __restrict__ Wout,
    const float* __restrict__ bout, float* __restrict__ y)
{
    __shared__ float Wt[64][33];
    __shared__ float Gt[32][68];
    const int n0 = blockIdx.x * 64;
    const int c0 = blockIdx.y * 64;
    const int b  = blockIdx.z;
    const int t = threadIdx.x;
    const int tx = t & 15, ty = t >> 4;

    float acc[4][4];
#pragma unroll
    for (int u = 0; u < 4; ++u)
#pragma unroll
        for (int v = 0; v < 4; ++v) acc[u][v] = 0.f;

    for (int kc = 0; kc < IC_; kc += 32) {
        __syncthreads();
#pragma unroll
        for (int s = 0; s < 2; ++s) {
            int e4 = t + 256 * s;
            int c = e4 >> 3, k4 = e4 & 7;
            float4 ww = *(const float4*)&Wout[(size_t)(c0 + c) * IC_ + kc + k4 * 4];
            Wt[c][k4 * 4 + 0] = ww.x; Wt[c][k4 * 4 + 1] = ww.y;
            Wt[c][k4 * 4 + 2] = ww.z; Wt[c][k4 * 4 + 3] = ww.w;
        }
#pragma unroll
        for (int s = 0; s < 2; ++s) {
            int e4 = t + 256 * s;
            int nn = e4 >> 3, k4 = e4 & 7;
            float4 g = *(const float4*)&gc[((size_t)b * N_ + n0 + nn) * IC_ + kc + k4 * 4];
            Gt[k4 * 4 + 0][nn] = g.x; Gt[k4 * 4 + 1][nn] = g.y;
            Gt[k4 * 4 + 2][nn] = g.z; Gt[k4 * 4 + 3][nn] = g.w;
        }
        __syncthreads();

#pragma unroll 4
        for (int k = 0; k < 32; ++k) {
            float a[4];
#pragma unroll
            for (int u = 0; u < 4; ++u) a[u] = Wt[ty * 4 + u][k];
            const float4 g4 = *(const float4*)&Gt[k][tx * 4];
            const float gm[4] = {g4.x, g4.y, g4.z, g4.w};
#pragma unroll
            for (int u = 0; u < 4; ++u)
#pragma unroll
                for (int v = 0; v < 4; ++v)
                    acc[u][v] = fmaf(a[u], gm[v], acc[u][v]);
        }
    }

#pragma unroll
    for (int u = 0; u < 4; ++u) {
        const int c = c0 + ty * 4 + u;
        const float bo = bout[c];
        *(float4*)&y[((size_t)b * C_ + c) * N_ + n0 + tx * 4] =
            make_float4(acc[u][0] + bo, acc[u][1] + bo,
                        acc[u][2] + bo, acc[u][3] + bo);
    }
}

// ---------------------------------------------------------------------------
// BatchNorm stats per channel
// ---------------------------------------------------------------------------
__global__ __launch_bounds__(256) void bn_stats_kernel(
    const float* __restrict__ y, float* __restrict__ mean,
    float* __restrict__ rsig)
{
    __shared__ float sr[8];
    const int c = blockIdx.x, t = threadIdx.x;
    const int lane = t & 63, wid = t >> 6;
    float s = 0.f, ss = 0.f;
    for (int b = 0; b < B_; ++b) {
        const float* yr = y + ((size_t)b * C_ + c) * N_;
        for (int n = t; n < N_; n += 256) {
            float v = yr[n];
            s += v; ss = fmaf(v, v, ss);
        }
    }
#pragma unroll
    for (int off = 32; off > 0; off >>= 1) {
        s  += __shfl_xor(s, off);
        ss += __shfl_xor(ss, off);
    }
    if (lane == 0) { sr[wid] = s; sr[4 + wid] = ss; }
    __syncthreads();
    if (t == 0) {
        float st  = sr[0] + sr[1] + sr[2] + sr[3];
        float sst = sr[4] + sr[5] + sr[6] + sr[7];
        float mu  = st / (float)(B_ * N_);
        float var = sst / (float)(B_ * N_) - mu * mu;
        mean[c] = mu;
        rsig[c] = rsqrtf(var + 1e-5f);
    }
}

// ---------------------------------------------------------------------------
// out = x + gamma*(y-mean)*rsig + beta
// ---------------------------------------------------------------------------
__global__ __launch_bounds__(256) void final_kernel(
    const float* __restrict__ x, const float* __restrict__ y,
    const float* __restrict__ mean, const float* __restrict__ rsig,
    const float* __restrict__ gamma, const float* __restrict__ beta,
    float* __restrict__ out)
{
    int idx = blockIdx.x * 256 + threadIdx.x;
    if (idx >= B_ * C_ * N_) return;
    int c = (idx >> 12) & (C_ - 1);
    out[idx] = x[idx] + fmaf(gamma[c], (y[idx] - mean[c]) * rsig[c], beta[c]);
}

extern "C" void kernel_launch(void* const* d_in, const int* in_sizes, int n_in,
                              void* d_out, int out_size, void* d_ws, size_t ws_size,
                              hipStream_t stream)
{
    const float* x     = (const float*)d_in[0];
    const float* hard  = (const float*)d_in[1];
    const float* Wg    = (const float*)d_in[2];
    const float* bg    = (const float*)d_in[3];
    const float* Wth   = (const float*)d_in[4];
    const float* bth   = (const float*)d_in[5];
    const float* Wph   = (const float*)d_in[6];
    const float* bph   = (const float*)d_in[7];
    const float* Wgcn  = (const float*)d_in[8];
    const float* Wout  = (const float*)d_in[9];
    const float* bout  = (const float*)d_in[10];
    const float* gamma = (const float*)d_in[11];
    const float* beta  = (const float*)d_in[12];
    float* out = (float*)d_out;
    float* ws  = (float*)d_ws;

    float* gc    = ws + OFF_GC;
    float* y     = ws + OFF_Y;
    float* mean  = ws + OFF_MEAN;
    float* rsig  = ws + OFF_RSIG;
    int*   cnt   = (int*)(ws + OFF_CNT);
    int*   list  = (int*)(ws + OFF_LIST);
    unsigned short* thetaH = (unsigned short*)(ws + OFF_THB);
    unsigned short* phiH   = (unsigned short*)(ws + OFF_PHB);
    unsigned short* gWTH   = (unsigned short*)(ws + OFF_GWT);
    unsigned short* xTH    = (unsigned short*)(ws + OFF_XTH);
    unsigned short* WallH  = (unsigned short*)(ws + OFF_WALL);
    float* ball  = ws + OFF_BALL;

    prep_kernel<<<dim3(1410), 256, 0, stream>>>(
        x, xTH, Wth, bth, Wg, bg, Wgcn, Wph, bph, WallH, ball,
        hard, cnt, list, gc);
    proj_kernel<<<dim3(N_ / 128, 3, B_), 256, 0, stream>>>(
        xTH, WallH, ball, thetaH, gWTH, phiH);
    attn_kernel<<<dim3(N_ / 16, B_), 512, 0, stream>>>(
        thetaH, phiH, gWTH, cnt, list, gc);
    y_kernel<<<dim3(N_ / 64, C_ / 64, B_), 256, 0, stream>>>(gc, Wout, bout, y);
    bn_stats_kernel<<<dim3(C_), 256, 0, stream>>>(y, mean, rsig);
    final_kernel<<<dim3(B_ * C_ * N_ / 256), 256, 0, stream>>>(
        x, y, mean, rsig, gamma, beta, out);
}

// Round 15
// 142.407 us; speedup vs baseline: 2.0896x; 2.0896x over previous
//
#include <hip/hip_runtime.h>

#define B_ 2
#define C_ 256
#define IC_ 128
#define N_ 4096
#define KSEL 2048
#define KS_PV 4
#define JCH (N_ / KS_PV)

// fixed workspace offsets (floats); SH + gc_part sized at runtime
#define OFF_GC    0u          // gc f32 [B][N][IC]
#define OFF_Y     1048576u    // y  f32 [B][C][N]
#define OFF_MEAN  3145728u
#define OFF_RSIG  3145984u
#define OFF_CNT   3146240u
#define OFF_LIST  3146304u    // int[B*N]
#define OFF_RANK  3154496u    // int[B*N]
#define OFF_THB   3162688u    // theta f16 [B][N][IC]
#define OFF_PHB   3686976u    // phi   f16 [B][N][IC]
#define OFF_GWT   4211264u    // gW^T  f16 [B][IC][N]
#define OFF_XTH   4735552u    // x^T   f16 [B][N][C]
#define OFF_WALL  5784128u    // {Wth,Weff,Wph} f16 [384][256]
#define OFF_BALL  5833280u    // f32 [384]
#define OFF_S     5833664u    // SH f16 [B][qr][N]; then gc_part f16

typedef __attribute__((ext_vector_type(8))) _Float16 f16x8;
typedef __attribute__((ext_vector_type(4))) float f32x4;

__device__ __forceinline__ unsigned short f2h(float f) {
    union { _Float16 h; unsigned short u; } cv;
    cv.h = (_Float16)f;
    return cv.u;
}
__device__ __forceinline__ float h2f(unsigned short u) {
    union { unsigned short u; _Float16 h; } cv;
    cv.u = u;
    return (float)cv.h;
}

// ---------------------------------------------------------------------------
// prep: fused {xT transpose (blocks 0..511), W pack + Weff (512..895),
//              hard-row compaction + rank map (896..897)}
// ---------------------------------------------------------------------------
__global__ __launch_bounds__(256) void prep_kernel(
    const float* __restrict__ x, unsigned short* __restrict__ xTH,
    const float* __restrict__ Wth, const float* __restrict__ bth,
    const float* __restrict__ Wg,  const float* __restrict__ bg,
    const float* __restrict__ Wgcn,
    const float* __restrict__ Wph, const float* __restrict__ bph,
    unsigned short* __restrict__ WallH, float* __restrict__ ball,
    const float* __restrict__ hard_map, int* __restrict__ cnt,
    int* __restrict__ list, int* __restrict__ rank)
{
    __shared__ float Xs[64][65];
    __shared__ int wsum[4];
    const int bid = blockIdx.x;
    const int t = threadIdx.x;

    if (bid < 512) {
        // ---- xT: x [b][c][n] f32 -> xTH [b][n][c] f16, 64x64 tile ----
        const int n0 = (bid & 63) * 64;
        const int c0 = ((bid >> 6) & 3) * 64;
        const int b  = bid >> 8;
#pragma unroll
        for (int s = 0; s < 4; ++s) {
            int e4 = t + 256 * s;
            int cc = e4 >> 4, c4 = e4 & 15;
            float4 v = *(const float4*)&x[((size_t)b * C_ + c0 + cc) * N_ + n0 + c4 * 4];
            Xs[cc][c4 * 4 + 0] = v.x; Xs[cc][c4 * 4 + 1] = v.y;
            Xs[cc][c4 * 4 + 2] = v.z; Xs[cc][c4 * 4 + 3] = v.w;
        }
        __syncthreads();
#pragma unroll
        for (int s = 0; s < 4; ++s) {
            int e = t + 256 * s;
            int nn = e >> 4, c4 = e & 15;
            ushort4 h;
            h.x = f2h(Xs[c4 * 4 + 0][nn]);
            h.y = f2h(Xs[c4 * 4 + 1][nn]);
            h.z = f2h(Xs[c4 * 4 + 2][nn]);
            h.w = f2h(Xs[c4 * 4 + 3][nn]);
            *(ushort4*)&xTH[((size_t)b * N_ + n0 + nn) * C_ + c0 + c4 * 4] = h;
        }
    } else if (bid < 896) {
        // ---- W pack: {Wth, Wgcn^T.Wg, Wph} -> WallH [384][256] + ball ----
        const int o = bid - 512;
        const int c = t;
        const int oo = o & 127;
        float wv, bv;
        if (o < 128) {
            wv = Wth[oo * C_ + c];
            bv = bth[oo];
        } else if (o < 256) {
            float acc = 0.f;
            for (int i = 0; i < IC_; ++i)
                acc = fmaf(Wgcn[i * IC_ + oo], Wg[i * C_ + c], acc);
            wv = acc;
            float bacc = 0.f;
            for (int i = 0; i < IC_; ++i)
                bacc = fmaf(Wgcn[i * IC_ + oo], bg[i], bacc);
            bv = bacc;
        } else {
            wv = Wph[oo * C_ + c];
            bv = bph[oo];
        }
        WallH[o * C_ + c] = f2h(wv);
        if (c == 0) ball[o] = bv;
    } else {
        // ---- compaction: 256 threads x 16 elements, atomic-free scan ----
        const int b = bid - 896;
        const int lane = t & 63, wid = t >> 6;
        const float* hm = hard_map + (size_t)b * N_;
        int flags[16];
        int c = 0;
#pragma unroll
        for (int q = 0; q < 4; ++q) {
            float4 v = *(const float4*)&hm[t * 16 + q * 4];
            flags[q * 4 + 0] = v.x > 0.5f;
            flags[q * 4 + 1] = v.y > 0.5f;
            flags[q * 4 + 2] = v.z > 0.5f;
            flags[q * 4 + 3] = v.w > 0.5f;
            c += flags[q * 4] + flags[q * 4 + 1] + flags[q * 4 + 2] + flags[q * 4 + 3];
        }
        int xv = c;
#pragma unroll
        for (int off = 1; off < 64; off <<= 1) {
            int y = __shfl_up(xv, off);
            if (lane >= off) xv += y;
        }
        if (lane == 63) wsum[wid] = xv;
        __syncthreads();
        int base = 0;
        for (int ww = 0; ww < wid; ++ww) base += wsum[ww];
        int pos = base + xv - c;
        int* lst = list + b * N_;
        int* rnk = rank + b * N_;
#pragma unroll
        for (int e = 0; e < 16; ++e) {
            int n = t * 16 + e;
            if (flags[e]) { lst[pos] = n; rnk[n] = pos; ++pos; }
            else rnk[n] = -1;
        }
        if (t == 0) {
            int tot = 0;
#pragma unroll
            for (int ww = 0; ww < 4; ++ww) tot += wsum[ww];
            cnt[b] = tot;
        }
    }
}

// ---------------------------------------------------------------------------
// proj (MFMA f16): out[o][n] = WallH[pj-chunk] . xT, K=256.
// grid (N/128, 3, B)
// ---------------------------------------------------------------------------
__global__ __launch_bounds__(256) void proj_kernel(
    const unsigned short* __restrict__ xTH,
    const unsigned short* __restrict__ WallH, const float* __restrict__ ball,
    unsigned short* __restrict__ thetaH, unsigned short* __restrict__ gWTH,
    unsigned short* __restrict__ phiH)
{
    __shared__ unsigned short Xt[128][72];
    __shared__ unsigned short Wt[128][72];
    const int n0 = blockIdx.x * 128;
    const int pj = blockIdx.y;
    const int b  = blockIdx.z;
    const int t = threadIdx.x, w = t >> 6, lane = t & 63;
    const int lrow = lane & 15, lk = (lane >> 4) * 8;
    const int wA = (w >> 1) * 64, wB = (w & 1) * 64;

    f32x4 acc[4][4];
#pragma unroll
    for (int u = 0; u < 4; ++u)
#pragma unroll
        for (int v = 0; v < 4; ++v) acc[u][v] = (f32x4)(0.f);

    for (int kc = 0; kc < C_; kc += 64) {
        __syncthreads();
#pragma unroll
        for (int s = 0; s < 4; ++s) {
            int e4 = t + 256 * s;
            int r = e4 >> 3, k8 = e4 & 7;
            *(float4*)&Xt[r][k8 * 8] =
                *(const float4*)&xTH[((size_t)b * N_ + n0 + r) * C_ + kc + k8 * 8];
        }
#pragma unroll
        for (int s = 0; s < 4; ++s) {
            int e4 = t + 256 * s;
            int r = e4 >> 3, k8 = e4 & 7;
            *(float4*)&Wt[r][k8 * 8] =
                *(const float4*)&WallH[(size_t)(pj * 128 + r) * C_ + kc + k8 * 8];
        }
        __syncthreads();

#pragma unroll
        for (int kstep = 0; kstep < 2; ++kstep) {
            const int kk = kstep * 32 + lk;
            f16x8 af[4], bf[4];
            if (pj != 1) {
#pragma unroll
                for (int u = 0; u < 4; ++u)
                    af[u] = *(const f16x8*)&Wt[wA + u * 16 + lrow][kk];
#pragma unroll
                for (int v = 0; v < 4; ++v)
                    bf[v] = *(const f16x8*)&Xt[wB + v * 16 + lrow][kk];
            } else {
#pragma unroll
                for (int u = 0; u < 4; ++u)
                    af[u] = *(const f16x8*)&Xt[wA + u * 16 + lrow][kk];
#pragma unroll
                for (int v = 0; v < 4; ++v)
                    bf[v] = *(const f16x8*)&Wt[wB + v * 16 + lrow][kk];
            }
#pragma unroll
            for (int u = 0; u < 4; ++u)
#pragma unroll
                for (int v = 0; v < 4; ++v)
                    acc[u][v] = __builtin_amdgcn_mfma_f32_16x16x32_f16(
                        af[u], bf[v], acc[u][v], 0, 0, 0);
        }
    }

    const int crow = (lane >> 4) * 4;
    if (pj != 1) {
        unsigned short* dst = (pj == 0) ? thetaH : phiH;
        const int bb2 = (pj == 0) ? 0 : 256;
#pragma unroll
        for (int u = 0; u < 4; ++u) {
            const int ob = wA + u * 16 + crow;
            float b0 = ball[bb2 + ob + 0], b1 = ball[bb2 + ob + 1];
            float b2 = ball[bb2 + ob + 2], b3 = ball[bb2 + ob + 3];
#pragma unroll
            for (int v = 0; v < 4; ++v) {
                const int n = n0 + wB + v * 16 + lrow;
                ushort4 h;
                h.x = f2h(acc[u][v][0] + b0);
                h.y = f2h(acc[u][v][1] + b1);
                h.z = f2h(acc[u][v][2] + b2);
                h.w = f2h(acc[u][v][3] + b3);
                *(ushort4*)&dst[((size_t)b * N_ + n) * IC_ + ob] = h;
            }
        }
    } else {
#pragma unroll
        for (int v = 0; v < 4; ++v) {
            const int o = wB + v * 16 + lrow;
            const float bo = ball[128 + o];
#pragma unroll
            for (int u = 0; u < 4; ++u) {
                const int nb = n0 + wA + u * 16 + crow;
                ushort4 h;
                h.x = f2h(acc[u][v][0] + bo);
                h.y = f2h(acc[u][v][1] + bo);
                h.z = f2h(acc[u][v][2] + bo);
                h.w = f2h(acc[u][v][3] + bo);
                *(ushort4*)&gWTH[((size_t)b * IC_ + o) * N_ + nb] = h;
            }
        }
    }
}

// ---------------------------------------------------------------------------
// score (MFMA f16): SH[b][lr][m] = theta_row(lr) . phi[:,m], f16 out.
// grid (N/128, qr/128, B)
// ---------------------------------------------------------------------------
__global__ __launch_bounds__(256) void score_kernel(
    const unsigned short* __restrict__ thetaH,
    const unsigned short* __restrict__ phiH,
    const int* __restrict__ cnt, const int* __restrict__ list,
    unsigned short* __restrict__ SH, int r0base, int qr)
{
    __shared__ unsigned short Th[128][136];
    __shared__ unsigned short Ph[128][136];
    __shared__ int sIdx[128];

    const int b = blockIdx.z;
    const int count = cnt[b];
    const int lr0 = blockIdx.y * 128;
    if (r0base + lr0 >= count) return;
    const int m0 = blockIdx.x * 128;
    const int t = threadIdx.x;
    const int w = t >> 6, lane = t & 63;

    if (t < 128) {
        int gr = r0base + lr0 + t;
        sIdx[t] = (gr < count) ? list[b * N_ + gr] : -1;
    }
    __syncthreads();

#pragma unroll
    for (int s = 0; s < 8; ++s) {
        int e4 = t + 256 * s;
        int r = e4 >> 4, k4 = e4 & 15;
        int gr = sIdx[r];
        float4 v = make_float4(0.f, 0.f, 0.f, 0.f);
        if (gr >= 0)
            v = *(const float4*)&thetaH[((size_t)b * N_ + gr) * IC_ + k4 * 8];
        *(float4*)&Th[r][k4 * 8] = v;
    }
#pragma unroll
    for (int s = 0; s < 8; ++s) {
        int e4 = t + 256 * s;
        int r = e4 >> 4, k4 = e4 & 15;
        *(float4*)&Ph[r][k4 * 8] =
            *(const float4*)&phiH[((size_t)b * N_ + m0 + r) * IC_ + k4 * 8];
    }
    __syncthreads();

    const int wm = (w >> 1) * 64, wr = (w & 1) * 64;
    const int lrow = lane & 15, lk = (lane >> 4) * 8;

    f32x4 acc[4][4];
#pragma unroll
    for (int u = 0; u < 4; ++u)
#pragma unroll
        for (int v = 0; v < 4; ++v) acc[u][v] = (f32x4)(0.f);

#pragma unroll
    for (int ks = 0; ks < 4; ++ks) {
        const int kk = ks * 32 + lk;
        f16x8 af[4], bf[4];
#pragma unroll
        for (int u = 0; u < 4; ++u)
            af[u] = *(const f16x8*)&Ph[wm + u * 16 + lrow][kk];
#pragma unroll
        for (int v = 0; v < 4; ++v)
            bf[v] = *(const f16x8*)&Th[wr + v * 16 + lrow][kk];
#pragma unroll
        for (int u = 0; u < 4; ++u)
#pragma unroll
            for (int v = 0; v < 4; ++v)
                acc[u][v] = __builtin_amdgcn_mfma_f32_16x16x32_f16(
                    af[u], bf[v], acc[u][v], 0, 0, 0);
    }

    const int crow = (lane >> 4) * 4;
#pragma unroll
    for (int u = 0; u < 4; ++u) {
        const int mb = m0 + wm + u * 16 + crow;
#pragma unroll
        for (int v = 0; v < 4; ++v) {
            const int r = lr0 + wr + v * 16 + lrow;
            ushort4 h;
            h.x = f2h(acc[u][v][0]);
            h.y = f2h(acc[u][v][1]);
            h.z = f2h(acc[u][v][2]);
            h.w = f2h(acc[u][v][3]);
            *(ushort4*)&SH[((size_t)b * qr + r) * N_ + mb] = h;
        }
    }
}

// ---------------------------------------------------------------------------
// select: exact kth-largest radix select (2x8-bit passes on monotone u16)
// + softmax; writes P f16 in place. grid (qr, B)
// ---------------------------------------------------------------------------
__global__ __launch_bounds__(256) void select_kernel(
    unsigned short* __restrict__ SH, const int* __restrict__ cnt,
    int r0base, int qr)
{
    __shared__ unsigned int sHist[4][256];
    __shared__ unsigned int sWsum[4];
    __shared__ float sRed[8];
    __shared__ unsigned int sPrefix, sRemain;

    const int b = blockIdx.y;
    const int lr = blockIdx.x;
    if (r0base + lr >= cnt[b]) return;
    const int t = threadIdx.x, lane = t & 63, wid = t >> 6;

    uint4* row = (uint4*)(SH + ((size_t)b * qr + lr) * N_);
    uint4 rv[2];
    rv[0] = row[t];
    rv[1] = row[t + 256];

    float sv[16];
    unsigned int mu[16];
#pragma unroll
    for (int q = 0; q < 2; ++q) {
        const unsigned int* pu = (const unsigned int*)&rv[q];
#pragma unroll
        for (int dw = 0; dw < 4; ++dw) {
            unsigned int u = pu[dw];
            unsigned short h0 = (unsigned short)(u & 0xffffu);
            unsigned short h1 = (unsigned short)(u >> 16);
            int e = q * 8 + dw * 2;
            sv[e]     = h2f(h0);
            sv[e + 1] = h2f(h1);
            mu[e]     = (h0 & 0x8000u) ? (unsigned int)((~h0) & 0xffffu)
                                       : (unsigned int)(h0 | 0x8000u);
            mu[e + 1] = (h1 & 0x8000u) ? (unsigned int)((~h1) & 0xffffu)
                                       : (unsigned int)(h1 | 0x8000u);
        }
    }

    float m = -3.4e38f;
#pragma unroll
    for (int e = 0; e < 16; ++e) m = fmaxf(m, sv[e]);
#pragma unroll
    for (int off = 32; off > 0; off >>= 1) m = fmaxf(m, __shfl_xor(m, off));
    if (lane == 0) sRed[wid] = m;
    __syncthreads();
    m = fmaxf(fmaxf(sRed[0], sRed[1]), fmaxf(sRed[2], sRed[3]));

    unsigned int prefix = 0u;
    unsigned int remain = KSEL;
    for (int d = 1; d >= 0; --d) {
        __syncthreads();
#pragma unroll
        for (int ww = 0; ww < 4; ++ww) sHist[ww][t] = 0u;
        __syncthreads();
#pragma unroll
        for (int e = 0; e < 16; ++e) {
            if ((mu[e] >> (8 * (d + 1))) == prefix)
                atomicAdd(&sHist[wid][(mu[e] >> (8 * d)) & 255u], 1u);
        }
        __syncthreads();
        unsigned int x = sHist[0][t] + sHist[1][t] + sHist[2][t] + sHist[3][t];
        unsigned int own = x;
#pragma unroll
        for (int off = 1; off < 64; off <<= 1) {
            unsigned int y = __shfl_down(x, off);
            if (lane + off < 64) x += y;
        }
        if (lane == 0) sWsum[wid] = x;
        __syncthreads();
        for (int ww = wid + 1; ww < 4; ++ww) x += sWsum[ww];
        unsigned int nxt = x - own;
        if (x >= remain && nxt < remain) {
            sPrefix = (prefix << 8) | (unsigned int)t;
            sRemain = remain - nxt;
        }
        __syncthreads();
        prefix = sPrefix;
        remain = sRemain;
    }
    const unsigned int tu = prefix;

    float z = 0.f, ssel = 0.f;
#pragma unroll
    for (int e = 0; e < 16; ++e) {
        float ex = expf(sv[e] - m);
        z += ex;
        if (mu[e] >= tu) ssel += ex;
    }
#pragma unroll
    for (int off = 32; off > 0; off >>= 1) {
        z    += __shfl_xor(z, off);
        ssel += __shfl_xor(ssel, off);
    }
    __syncthreads();
    if (lane == 0) { sRed[wid] = z; sRed[4 + wid] = ssel; }
    __syncthreads();
    const float zt = sRed[0] + sRed[1] + sRed[2] + sRed[3];
    const float st = sRed[4] + sRed[5] + sRed[6] + sRed[7];
    const float inv = 1.f / (st + 1e-6f * zt);

#pragma unroll
    for (int q = 0; q < 2; ++q) {
        unsigned int* pu = (unsigned int*)&rv[q];
#pragma unroll
        for (int dw = 0; dw < 4; ++dw) {
            int e = q * 8 + dw * 2;
            unsigned int p0 = (mu[e] >= tu) ? (unsigned int)f2h(expf(sv[e] - m) * inv) : 0u;
            unsigned int p1 = (mu[e + 1] >= tu) ? (unsigned int)f2h(expf(sv[e + 1] - m) * inv) : 0u;
            pu[dw] = p0 | (p1 << 16);
        }
    }
    row[t]       = rv[0];
    row[t + 256] = rv[1];
}

// ---------------------------------------------------------------------------
// pv (MFMA f16, split-K=4): gc_partH[b][ks][lr][i] (f16) over ks*JCH..+JCH.
// grid (qr/64, KS_PV, B)
// ---------------------------------------------------------------------------
__global__ __launch_bounds__(256) void pv_kernel(
    const unsigned short* __restrict__ SH, const unsigned short* __restrict__ gWTH,
    const int* __restrict__ cnt, unsigned short* __restrict__ gc_partH,
    int r0base, int qr)
{
    __shared__ unsigned short Pt[64][72];
    __shared__ unsigned short Gt[128][72];

    const int b = blockIdx.z;
    const int count = cnt[b];
    const int lr0 = blockIdx.x * 64;
    if (r0base + lr0 >= count) return;
    const int ks = blockIdx.y;
    const int t = threadIdx.x;
    const int w = t >> 6, lane = t & 63;
    const int lrow = lane & 15, lk = (lane >> 4) * 8;
    const int wiA = (w & 1) * 64, wrB = (w >> 1) * 32;

    f32x4 acc[4][2];
#pragma unroll
    for (int u = 0; u < 4; ++u)
#pragma unroll
        for (int v = 0; v < 2; ++v) acc[u][v] = (f32x4)(0.f);

    for (int jc = ks * JCH; jc < ks * JCH + JCH; jc += 64) {
        __syncthreads();
#pragma unroll
        for (int s = 0; s < 2; ++s) {
            int e4 = t + 256 * s;
            int r = e4 >> 3, k8 = e4 & 7;
            *(float4*)&Pt[r][k8 * 8] =
                *(const float4*)&SH[((size_t)b * qr + lr0 + r) * N_ + jc + k8 * 8];
        }
#pragma unroll
        for (int s = 0; s < 4; ++s) {
            int e4 = t + 256 * s;
            int i = e4 >> 3, k8 = e4 & 7;
            *(float4*)&Gt[i][k8 * 8] =
                *(const float4*)&gWTH[((size_t)b * IC_ + i) * N_ + jc + k8 * 8];
        }
        __syncthreads();

#pragma unroll
        for (int kstep = 0; kstep < 2; ++kstep) {
            const int kk = kstep * 32 + lk;
            f16x8 af[4], bf[2];
#pragma unroll
            for (int u = 0; u < 4; ++u)
                af[u] = *(const f16x8*)&Gt[wiA + u * 16 + lrow][kk];
#pragma unroll
            for (int v = 0; v < 2; ++v)
                bf[v] = *(const f16x8*)&Pt[wrB + v * 16 + lrow][kk];
#pragma unroll
            for (int u = 0; u < 4; ++u)
#pragma unroll
                for (int v = 0; v < 2; ++v)
                    acc[u][v] = __builtin_amdgcn_mfma_f32_16x16x32_f16(
                        af[u], bf[v], acc[u][v], 0, 0, 0);
        }
    }

    const int crow = (lane >> 4) * 4;
#pragma unroll
    for (int u = 0; u < 4; ++u) {
        const int ib = wiA + u * 16 + crow;
#pragma unroll
        for (int v = 0; v < 2; ++v) {
            const int r = lr0 + wrB + v * 16 + lrow;
            ushort4 h;
            h.x = f2h(acc[u][v][0]);
            h.y = f2h(acc[u][v][1]);
            h.z = f2h(acc[u][v][2]);
            h.w = f2h(acc[u][v][3]);
            *(ushort4*)&gc_partH[(((size_t)b * KS_PV + ks) * qr + r) * IC_ + ib] = h;
        }
    }
}

// ---------------------------------------------------------------------------
// dense scatter: for every (b,n,i) — rank<0 -> 0 (pass 0 only), else reduce
// f16 split-K partials + ReLU. grid (N*IC/256, B)
// ---------------------------------------------------------------------------
__global__ __launch_bounds__(256) void scatter_kernel(
    const unsigned short* __restrict__ gc_partH, const int* __restrict__ rank,
    float* __restrict__ gc, int r0base, int qr)
{
    const int b = blockIdx.y;
    int idx = blockIdx.x * 256 + threadIdx.x;
    int n = idx >> 7, i = idx & 127;
    int r = rank[b * N_ + n];
    if (r < 0) {
        if (r0base == 0) gc[((size_t)b * N_ + n) * IC_ + i] = 0.f;
        return;
    }
    if (r < r0base || r >= r0base + qr) return;
    const int lr = r - r0base;
    float v = 0.f;
#pragma unroll
    for (int ks = 0; ks < KS_PV; ++ks)
        v += h2f(gc_partH[(((size_t)b * KS_PV + ks) * qr + lr) * IC_ + i]);
    gc[((size_t)b * N_ + n) * IC_ + i] = fmaxf(v, 0.f);
}

// ---------------------------------------------------------------------------
// y[b,c,n] = Wout[c,:] . gc[b,n,:] + bout[c].  64c x 64n tiles.
// ---------------------------------------------------------------------------
__global__ __launch_bounds__(256) void y_kernel(
    const float* __restrict__ gc, const float* __restrict__ Wout,
    const float* __restrict__ bout, float* __restrict__ y)
{
    __shared__ float Wt[64][33];
    __shared__ float Gt[32][68];
    const int n0 = blockIdx.x * 64;
    const int c0 = blockIdx.y * 64;
    const int b  = blockIdx.z;
    const int t = threadIdx.x;
    const int tx = t & 15, ty = t >> 4;

    float acc[4][4];
#pragma unroll
    for (int u = 0; u < 4; ++u)
#pragma unroll
        for (int v = 0; v < 4; ++v) acc[u][v] = 0.f;

    for (int kc = 0; kc < IC_; kc += 32) {
        __syncthreads();
#pragma unroll
        for (int s = 0; s < 2; ++s) {
            int e4 = t + 256 * s;
            int c = e4 >> 3, k4 = e4 & 7;
            float4 ww = *(const float4*)&Wout[(size_t)(c0 + c) * IC_ + kc + k4 * 4];
            Wt[c][k4 * 4 + 0] = ww.x; Wt[c][k4 * 4 + 1] = ww.y;
            Wt[c][k4 * 4 + 2] = ww.z; Wt[c][k4 * 4 + 3] = ww.w;
        }
#pragma unroll
        for (int s = 0; s < 2; ++s) {
            int e4 = t + 256 * s;
            int nn = e4 >> 3, k4 = e4 & 7;
            float4 g = *(const float4*)&gc[((size_t)b * N_ + n0 + nn) * IC_ + kc + k4 * 4];
            Gt[k4 * 4 + 0][nn] = g.x; Gt[k4 * 4 + 1][nn] = g.y;
            Gt[k4 * 4 + 2][nn] = g.z; Gt[k4 * 4 + 3][nn] = g.w;
        }
        __syncthreads();

#pragma unroll 4
        for (int k = 0; k < 32; ++k) {
            float a[4];
#pragma unroll
            for (int u = 0; u < 4; ++u) a[u] = Wt[ty * 4 + u][k];
            const float4 g4 = *(const float4*)&Gt[k][tx * 4];
            const float gm[4] = {g4.x, g4.y, g4.z, g4.w};
#pragma unroll
            for (int u = 0; u < 4; ++u)
#pragma unroll
                for (int v = 0; v < 4; ++v)
                    acc[u][v] = fmaf(a[u], gm[v], acc[u][v]);
        }
    }

#pragma unroll
    for (int u = 0; u < 4; ++u) {
        const int c = c0 + ty * 4 + u;
        const float bo = bout[c];
        *(float4*)&y[((size_t)b * C_ + c) * N_ + n0 + tx * 4] =
            make_float4(acc[u][0] + bo, acc[u][1] + bo,
                        acc[u][2] + bo, acc[u][3] + bo);
    }
}

// ---------------------------------------------------------------------------
// BatchNorm stats per channel
// ---------------------------------------------------------------------------
__global__ __launch_bounds__(256) void bn_stats_kernel(
    const float* __restrict__ y, float* __restrict__ mean,
    float* __restrict__ rsig)
{
    __shared__ float sr[8];
    const int c = blockIdx.x, t = threadIdx.x;
    const int lane = t & 63, wid = t >> 6;
    float s = 0.f, ss = 0.f;
    for (int b = 0; b < B_; ++b) {
        const float* yr = y + ((size_t)b * C_ + c) * N_;
        for (int n = t; n < N_; n += 256) {
            float v = yr[n];
            s += v; ss = fmaf(v, v, ss);
        }
    }
#pragma unroll
    for (int off = 32; off > 0; off >>= 1) {
        s  += __shfl_xor(s, off);
        ss += __shfl_xor(ss, off);
    }
    if (lane == 0) { sr[wid] = s; sr[4 + wid] = ss; }
    __syncthreads();
    if (t == 0) {
        float st  = sr[0] + sr[1] + sr[2] + sr[3];
        float sst = sr[4] + sr[5] + sr[6] + sr[7];
        float mu  = st / (float)(B_ * N_);
        float var = sst / (float)(B_ * N_) - mu * mu;
        mean[c] = mu;
        rsig[c] = rsqrtf(var + 1e-5f);
    }
}

// ---------------------------------------------------------------------------
// out = x + gamma*(y-mean)*rsig + beta
// ---------------------------------------------------------------------------
__global__ __launch_bounds__(256) void final_kernel(
    const float* __restrict__ x, const float* __restrict__ y,
    const float* __restrict__ mean, const float* __restrict__ rsig,
    const float* __restrict__ gamma, const float* __restrict__ beta,
    float* __restrict__ out)
{
    int idx = blockIdx.x * 256 + threadIdx.x;
    if (idx >= B_ * C_ * N_) return;
    int c = (idx >> 12) & (C_ - 1);
    out[idx] = x[idx] + fmaf(gamma[c], (y[idx] - mean[c]) * rsig[c], beta[c]);
}

extern "C" void kernel_launch(void* const* d_in, const int* in_sizes, int n_in,
                              void* d_out, int out_size, void* d_ws, size_t ws_size,
                              hipStream_t stream)
{
    const float* x     = (const float*)d_in[0];
    const float* hard  = (const float*)d_in[1];
    const float* Wg    = (const float*)d_in[2];
    const float* bg    = (const float*)d_in[3];
    const float* Wth   = (const float*)d_in[4];
    const float* bth   = (const float*)d_in[5];
    const float* Wph   = (const float*)d_in[6];
    const float* bph   = (const float*)d_in[7];
    const float* Wgcn  = (const float*)d_in[8];
    const float* Wout  = (const float*)d_in[9];
    const float* bout  = (const float*)d_in[10];
    const float* gamma = (const float*)d_in[11];
    const float* beta  = (const float*)d_in[12];
    float* out = (float*)d_out;
    float* ws  = (float*)d_ws;

    float* gc    = ws + OFF_GC;
    float* y     = ws + OFF_Y;
    float* mean  = ws + OFF_MEAN;
    float* rsig  = ws + OFF_RSIG;
    int*   cnt   = (int*)(ws + OFF_CNT);
    int*   list  = (int*)(ws + OFF_LIST);
    int*   rank  = (int*)(ws + OFF_RANK);
    unsigned short* thetaH = (unsigned short*)(ws + OFF_THB);
    unsigned short* phiH   = (unsigned short*)(ws + OFF_PHB);
    unsigned short* gWTH   = (unsigned short*)(ws + OFF_GWT);
    unsigned short* xTH    = (unsigned short*)(ws + OFF_XTH);
    unsigned short* WallH  = (unsigned short*)(ws + OFF_WALL);
    float* ball  = ws + OFF_BALL;
    unsigned short* SH = (unsigned short*)(ws + OFF_S);

    // runtime-adaptive row-block; partials f16
    const size_t wsf = ws_size / sizeof(float);
    int qr;
    unsigned short* gc_partH;
    if (wsf >= OFF_S + (size_t)4096 * 6144) {            // >= 124 MB total
        qr = 4096; gc_partH = (unsigned short*)(ws + OFF_S + (size_t)4096 * 4096);
    } else if (wsf >= OFF_S + (size_t)2048 * 6144) {
        qr = 2048; gc_partH = (unsigned short*)(ws + OFF_S + (size_t)2048 * 4096);
    } else {
        qr = 1024; gc_partH = (unsigned short*)out;  // 2.1 MB < 8 MB d_out;
                                                     // overwritten by final
    }

    prep_kernel<<<dim3(898), 256, 0, stream>>>(
        x, xTH, Wth, bth, Wg, bg, Wgcn, Wph, bph, WallH, ball,
        hard, cnt, list, rank);
    proj_kernel<<<dim3(N_ / 128, 3, B_), 256, 0, stream>>>(
        xTH, WallH, ball, thetaH, gWTH, phiH);

    for (int r0 = 0; r0 < N_; r0 += qr) {
        score_kernel<<<dim3(N_ / 128, qr / 128, B_), 256, 0, stream>>>(
            thetaH, phiH, cnt, list, SH, r0, qr);
        select_kernel<<<dim3(qr, B_), 256, 0, stream>>>(SH, cnt, r0, qr);
        pv_kernel<<<dim3(qr / 64, KS_PV, B_), 256, 0, stream>>>(
            SH, gWTH, cnt, gc_partH, r0, qr);
        scatter_kernel<<<dim3(N_ * IC_ / 256, B_), 256, 0, stream>>>(
            gc_partH, rank, gc, r0, qr);
    }

    y_kernel<<<dim3(N_ / 64, C_ / 64, B_), 256, 0, stream>>>(gc, Wout, bout, y);
    bn_stats_kernel<<<dim3(C_), 256, 0, stream>>>(y, mean, rsig);
    final_kernel<<<dim3(B_ * C_ * N_ / 256), 256, 0, stream>>>(
        x, y, mean, rsig, gamma, beta, out);
}

// Round 16
// 132.797 us; speedup vs baseline: 2.2408x; 1.0724x over previous
//
#include <hip/hip_runtime.h>

#define B_ 2
#define C_ 256
#define IC_ 128
#define N_ 4096
#define KSEL 2048
#define KS_PV 16
#define JCH (N_ / KS_PV)

// fixed workspace offsets (floats); SH + gc_part sized at runtime
#define OFF_GC    0u          // gc f32 [B][N][IC]
#define OFF_Y     1048576u    // y  f32 [B][C][N]
#define OFF_MEAN  3145728u
#define OFF_RSIG  3145984u
#define OFF_CNT   3146240u
#define OFF_LIST  3146304u    // int[B*N]
#define OFF_RANK  3154496u    // int[B*N]
#define OFF_THB   3162688u    // theta f16 [B][N][IC]
#define OFF_PHB   3686976u    // phi   f16 [B][N][IC]
#define OFF_GWT   4211264u    // gW^T  f16 [B][IC][N]
#define OFF_XTH   4735552u    // x^T   f16 [B][N][C]
#define OFF_WALL  5784128u    // {Wth,Weff,Wph} f16 [384][256]
#define OFF_BALL  5833280u    // f32 [384]
#define OFF_S     5833664u    // SH f16 [B][qr][N]; then gc_part f16

typedef __attribute__((ext_vector_type(8))) _Float16 f16x8;
typedef __attribute__((ext_vector_type(4))) float f32x4;

__device__ __forceinline__ unsigned short f2h(float f) {
    union { _Float16 h; unsigned short u; } cv;
    cv.h = (_Float16)f;
    return cv.u;
}
__device__ __forceinline__ float h2f(unsigned short u) {
    union { unsigned short u; _Float16 h; } cv;
    cv.u = u;
    return (float)cv.h;
}

// ---------------------------------------------------------------------------
// prep: fused {xT transpose (blocks 0..511), W pack + Weff (512..895),
//              hard-row compaction + rank map (896..897)}
// ---------------------------------------------------------------------------
__global__ __launch_bounds__(256) void prep_kernel(
    const float* __restrict__ x, unsigned short* __restrict__ xTH,
    const float* __restrict__ Wth, const float* __restrict__ bth,
    const float* __restrict__ Wg,  const float* __restrict__ bg,
    const float* __restrict__ Wgcn,
    const float* __restrict__ Wph, const float* __restrict__ bph,
    unsigned short* __restrict__ WallH, float* __restrict__ ball,
    const float* __restrict__ hard_map, int* __restrict__ cnt,
    int* __restrict__ list, int* __restrict__ rank)
{
    __shared__ float Xs[64][65];
    __shared__ int wsum[4];
    const int bid = blockIdx.x;
    const int t = threadIdx.x;

    if (bid < 512) {
        // ---- xT: x [b][c][n] f32 -> xTH [b][n][c] f16, 64x64 tile ----
        const int n0 = (bid & 63) * 64;
        const int c0 = ((bid >> 6) & 3) * 64;
        const int b  = bid >> 8;
#pragma unroll
        for (int s = 0; s < 4; ++s) {
            int e4 = t + 256 * s;
            int cc = e4 >> 4, c4 = e4 & 15;
            float4 v = *(const float4*)&x[((size_t)b * C_ + c0 + cc) * N_ + n0 + c4 * 4];
            Xs[cc][c4 * 4 + 0] = v.x; Xs[cc][c4 * 4 + 1] = v.y;
            Xs[cc][c4 * 4 + 2] = v.z; Xs[cc][c4 * 4 + 3] = v.w;
        }
        __syncthreads();
#pragma unroll
        for (int s = 0; s < 4; ++s) {
            int e = t + 256 * s;
            int nn = e >> 4, c4 = e & 15;
            ushort4 h;
            h.x = f2h(Xs[c4 * 4 + 0][nn]);
            h.y = f2h(Xs[c4 * 4 + 1][nn]);
            h.z = f2h(Xs[c4 * 4 + 2][nn]);
            h.w = f2h(Xs[c4 * 4 + 3][nn]);
            *(ushort4*)&xTH[((size_t)b * N_ + n0 + nn) * C_ + c0 + c4 * 4] = h;
        }
    } else if (bid < 896) {
        // ---- W pack: {Wth, Wgcn^T.Wg, Wph} -> WallH [384][256] + ball ----
        const int o = bid - 512;
        const int c = t;
        const int oo = o & 127;
        float wv, bv;
        if (o < 128) {
            wv = Wth[oo * C_ + c];
            bv = bth[oo];
        } else if (o < 256) {
            float acc = 0.f;
            for (int i = 0; i < IC_; ++i)
                acc = fmaf(Wgcn[i * IC_ + oo], Wg[i * C_ + c], acc);
            wv = acc;
            float bacc = 0.f;
            for (int i = 0; i < IC_; ++i)
                bacc = fmaf(Wgcn[i * IC_ + oo], bg[i], bacc);
            bv = bacc;
        } else {
            wv = Wph[oo * C_ + c];
            bv = bph[oo];
        }
        WallH[o * C_ + c] = f2h(wv);
        if (c == 0) ball[o] = bv;
    } else {
        // ---- compaction: 256 threads x 16 elements, atomic-free scan ----
        const int b = bid - 896;
        const int lane = t & 63, wid = t >> 6;
        const float* hm = hard_map + (size_t)b * N_;
        int flags[16];
        int c = 0;
#pragma unroll
        for (int q = 0; q < 4; ++q) {
            float4 v = *(const float4*)&hm[t * 16 + q * 4];
            flags[q * 4 + 0] = v.x > 0.5f;
            flags[q * 4 + 1] = v.y > 0.5f;
            flags[q * 4 + 2] = v.z > 0.5f;
            flags[q * 4 + 3] = v.w > 0.5f;
            c += flags[q * 4] + flags[q * 4 + 1] + flags[q * 4 + 2] + flags[q * 4 + 3];
        }
        int xv = c;
#pragma unroll
        for (int off = 1; off < 64; off <<= 1) {
            int y = __shfl_up(xv, off);
            if (lane >= off) xv += y;
        }
        if (lane == 63) wsum[wid] = xv;
        __syncthreads();
        int base = 0;
        for (int ww = 0; ww < wid; ++ww) base += wsum[ww];
        int pos = base + xv - c;
        int* lst = list + b * N_;
        int* rnk = rank + b * N_;
#pragma unroll
        for (int e = 0; e < 16; ++e) {
            int n = t * 16 + e;
            if (flags[e]) { lst[pos] = n; rnk[n] = pos; ++pos; }
            else rnk[n] = -1;
        }
        if (t == 0) {
            int tot = 0;
#pragma unroll
            for (int ww = 0; ww < 4; ++ww) tot += wsum[ww];
            cnt[b] = tot;
        }
    }
}

// ---------------------------------------------------------------------------
// proj (MFMA f16): out[o][n] = WallH[pj-chunk] . xT, K=256.
// grid (N/128, 3, B)
// ---------------------------------------------------------------------------
__global__ __launch_bounds__(256) void proj_kernel(
    const unsigned short* __restrict__ xTH,
    const unsigned short* __restrict__ WallH, const float* __restrict__ ball,
    unsigned short* __restrict__ thetaH, unsigned short* __restrict__ gWTH,
    unsigned short* __restrict__ phiH)
{
    __shared__ unsigned short Xt[128][72];
    __shared__ unsigned short Wt[128][72];
    const int n0 = blockIdx.x * 128;
    const int pj = blockIdx.y;
    const int b  = blockIdx.z;
    const int t = threadIdx.x, w = t >> 6, lane = t & 63;
    const int lrow = lane & 15, lk = (lane >> 4) * 8;
    const int wA = (w >> 1) * 64, wB = (w & 1) * 64;

    f32x4 acc[4][4];
#pragma unroll
    for (int u = 0; u < 4; ++u)
#pragma unroll
        for (int v = 0; v < 4; ++v) acc[u][v] = (f32x4)(0.f);

    for (int kc = 0; kc < C_; kc += 64) {
        __syncthreads();
#pragma unroll
        for (int s = 0; s < 4; ++s) {
            int e4 = t + 256 * s;
            int r = e4 >> 3, k8 = e4 & 7;
            *(float4*)&Xt[r][k8 * 8] =
                *(const float4*)&xTH[((size_t)b * N_ + n0 + r) * C_ + kc + k8 * 8];
        }
#pragma unroll
        for (int s = 0; s < 4; ++s) {
            int e4 = t + 256 * s;
            int r = e4 >> 3, k8 = e4 & 7;
            *(float4*)&Wt[r][k8 * 8] =
                *(const float4*)&WallH[(size_t)(pj * 128 + r) * C_ + kc + k8 * 8];
        }
        __syncthreads();

#pragma unroll
        for (int kstep = 0; kstep < 2; ++kstep) {
            const int kk = kstep * 32 + lk;
            f16x8 af[4], bf[4];
            if (pj != 1) {
#pragma unroll
                for (int u = 0; u < 4; ++u)
                    af[u] = *(const f16x8*)&Wt[wA + u * 16 + lrow][kk];
#pragma unroll
                for (int v = 0; v < 4; ++v)
                    bf[v] = *(const f16x8*)&Xt[wB + v * 16 + lrow][kk];
            } else {
#pragma unroll
                for (int u = 0; u < 4; ++u)
                    af[u] = *(const f16x8*)&Xt[wA + u * 16 + lrow][kk];
#pragma unroll
                for (int v = 0; v < 4; ++v)
                    bf[v] = *(const f16x8*)&Wt[wB + v * 16 + lrow][kk];
            }
#pragma unroll
            for (int u = 0; u < 4; ++u)
#pragma unroll
                for (int v = 0; v < 4; ++v)
                    acc[u][v] = __builtin_amdgcn_mfma_f32_16x16x32_f16(
                        af[u], bf[v], acc[u][v], 0, 0, 0);
        }
    }

    const int crow = (lane >> 4) * 4;
    if (pj != 1) {
        unsigned short* dst = (pj == 0) ? thetaH : phiH;
        const int bb2 = (pj == 0) ? 0 : 256;
#pragma unroll
        for (int u = 0; u < 4; ++u) {
            const int ob = wA + u * 16 + crow;
            float b0 = ball[bb2 + ob + 0], b1 = ball[bb2 + ob + 1];
            float b2 = ball[bb2 + ob + 2], b3 = ball[bb2 + ob + 3];
#pragma unroll
            for (int v = 0; v < 4; ++v) {
                const int n = n0 + wB + v * 16 + lrow;
                ushort4 h;
                h.x = f2h(acc[u][v][0] + b0);
                h.y = f2h(acc[u][v][1] + b1);
                h.z = f2h(acc[u][v][2] + b2);
                h.w = f2h(acc[u][v][3] + b3);
                *(ushort4*)&dst[((size_t)b * N_ + n) * IC_ + ob] = h;
            }
        }
    } else {
#pragma unroll
        for (int v = 0; v < 4; ++v) {
            const int o = wB + v * 16 + lrow;
            const float bo = ball[128 + o];
#pragma unroll
            for (int u = 0; u < 4; ++u) {
                const int nb = n0 + wA + u * 16 + crow;
                ushort4 h;
                h.x = f2h(acc[u][v][0] + bo);
                h.y = f2h(acc[u][v][1] + bo);
                h.z = f2h(acc[u][v][2] + bo);
                h.w = f2h(acc[u][v][3] + bo);
                *(ushort4*)&gWTH[((size_t)b * IC_ + o) * N_ + nb] = h;
            }
        }
    }
}

// ---------------------------------------------------------------------------
// score (MFMA f16): SH[b][lr][m] = theta_row(lr) . phi[:,m], f16 out.
// grid (N/128, qr/128, B)
// ---------------------------------------------------------------------------
__global__ __launch_bounds__(256) void score_kernel(
    const unsigned short* __restrict__ thetaH,
    const unsigned short* __restrict__ phiH,
    const int* __restrict__ cnt, const int* __restrict__ list,
    unsigned short* __restrict__ SH, int r0base, int qr)
{
    __shared__ unsigned short Th[128][136];
    __shared__ unsigned short Ph[128][136];
    __shared__ int sIdx[128];

    const int b = blockIdx.z;
    const int count = cnt[b];
    const int lr0 = blockIdx.y * 128;
    if (r0base + lr0 >= count) return;
    const int m0 = blockIdx.x * 128;
    const int t = threadIdx.x;
    const int w = t >> 6, lane = t & 63;

    if (t < 128) {
        int gr = r0base + lr0 + t;
        sIdx[t] = (gr < count) ? list[b * N_ + gr] : -1;
    }
    __syncthreads();

#pragma unroll
    for (int s = 0; s < 8; ++s) {
        int e4 = t + 256 * s;
        int r = e4 >> 4, k4 = e4 & 15;
        int gr = sIdx[r];
        float4 v = make_float4(0.f, 0.f, 0.f, 0.f);
        if (gr >= 0)
            v = *(const float4*)&thetaH[((size_t)b * N_ + gr) * IC_ + k4 * 8];
        *(float4*)&Th[r][k4 * 8] = v;
    }
#pragma unroll
    for (int s = 0; s < 8; ++s) {
        int e4 = t + 256 * s;
        int r = e4 >> 4, k4 = e4 & 15;
        *(float4*)&Ph[r][k4 * 8] =
            *(const float4*)&phiH[((size_t)b * N_ + m0 + r) * IC_ + k4 * 8];
    }
    __syncthreads();

    const int wm = (w >> 1) * 64, wr = (w & 1) * 64;
    const int lrow = lane & 15, lk = (lane >> 4) * 8;

    f32x4 acc[4][4];
#pragma unroll
    for (int u = 0; u < 4; ++u)
#pragma unroll
        for (int v = 0; v < 4; ++v) acc[u][v] = (f32x4)(0.f);

#pragma unroll
    for (int ks = 0; ks < 4; ++ks) {
        const int kk = ks * 32 + lk;
        f16x8 af[4], bf[4];
#pragma unroll
        for (int u = 0; u < 4; ++u)
            af[u] = *(const f16x8*)&Ph[wm + u * 16 + lrow][kk];
#pragma unroll
        for (int v = 0; v < 4; ++v)
            bf[v] = *(const f16x8*)&Th[wr + v * 16 + lrow][kk];
#pragma unroll
        for (int u = 0; u < 4; ++u)
#pragma unroll
            for (int v = 0; v < 4; ++v)
                acc[u][v] = __builtin_amdgcn_mfma_f32_16x16x32_f16(
                    af[u], bf[v], acc[u][v], 0, 0, 0);
    }

    const int crow = (lane >> 4) * 4;
#pragma unroll
    for (int u = 0; u < 4; ++u) {
        const int mb = m0 + wm + u * 16 + crow;
#pragma unroll
        for (int v = 0; v < 4; ++v) {
            const int r = lr0 + wr + v * 16 + lrow;
            ushort4 h;
            h.x = f2h(acc[u][v][0]);
            h.y = f2h(acc[u][v][1]);
            h.z = f2h(acc[u][v][2]);
            h.w = f2h(acc[u][v][3]);
            *(ushort4*)&SH[((size_t)b * qr + r) * N_ + mb] = h;
        }
    }
}

// ---------------------------------------------------------------------------
// select: exact kth-largest radix select (2x8-bit passes on monotone u16)
// + softmax; writes P f16 in place. grid (qr, B)
// ---------------------------------------------------------------------------
__global__ __launch_bounds__(256) void select_kernel(
    unsigned short* __restrict__ SH, const int* __restrict__ cnt,
    int r0base, int qr)
{
    __shared__ unsigned int sHist[4][256];
    __shared__ unsigned int sWsum[4];
    __shared__ float sRed[8];
    __shared__ unsigned int sPrefix, sRemain;

    const int b = blockIdx.y;
    const int lr = blockIdx.x;
    if (r0base + lr >= cnt[b]) return;
    const int t = threadIdx.x, lane = t & 63, wid = t >> 6;

    uint4* row = (uint4*)(SH + ((size_t)b * qr + lr) * N_);
    uint4 rv[2];
    rv[0] = row[t];
    rv[1] = row[t + 256];

    float sv[16];
    unsigned int mu[16];
#pragma unroll
    for (int q = 0; q < 2; ++q) {
        const unsigned int* pu = (const unsigned int*)&rv[q];
#pragma unroll
        for (int dw = 0; dw < 4; ++dw) {
            unsigned int u = pu[dw];
            unsigned short h0 = (unsigned short)(u & 0xffffu);
            unsigned short h1 = (unsigned short)(u >> 16);
            int e = q * 8 + dw * 2;
            sv[e]     = h2f(h0);
            sv[e + 1] = h2f(h1);
            mu[e]     = (h0 & 0x8000u) ? (unsigned int)((~h0) & 0xffffu)
                                       : (unsigned int)(h0 | 0x8000u);
            mu[e + 1] = (h1 & 0x8000u) ? (unsigned int)((~h1) & 0xffffu)
                                       : (unsigned int)(h1 | 0x8000u);
        }
    }

    float m = -3.4e38f;
#pragma unroll
    for (int e = 0; e < 16; ++e) m = fmaxf(m, sv[e]);
#pragma unroll
    for (int off = 32; off > 0; off >>= 1) m = fmaxf(m, __shfl_xor(m, off));
    if (lane == 0) sRed[wid] = m;
    __syncthreads();
    m = fmaxf(fmaxf(sRed[0], sRed[1]), fmaxf(sRed[2], sRed[3]));

    unsigned int prefix = 0u;
    unsigned int remain = KSEL;
    for (int d = 1; d >= 0; --d) {
        __syncthreads();
#pragma unroll
        for (int ww = 0; ww < 4; ++ww) sHist[ww][t] = 0u;
        __syncthreads();
#pragma unroll
        for (int e = 0; e < 16; ++e) {
            if ((mu[e] >> (8 * (d + 1))) == prefix)
                atomicAdd(&sHist[wid][(mu[e] >> (8 * d)) & 255u], 1u);
        }
        __syncthreads();
        unsigned int x = sHist[0][t] + sHist[1][t] + sHist[2][t] + sHist[3][t];
        unsigned int own = x;
#pragma unroll
        for (int off = 1; off < 64; off <<= 1) {
            unsigned int y = __shfl_down(x, off);
            if (lane + off < 64) x += y;
        }
        if (lane == 0) sWsum[wid] = x;
        __syncthreads();
        for (int ww = wid + 1; ww < 4; ++ww) x += sWsum[ww];
        unsigned int nxt = x - own;
        if (x >= remain && nxt < remain) {
            sPrefix = (prefix << 8) | (unsigned int)t;
            sRemain = remain - nxt;
        }
        __syncthreads();
        prefix = sPrefix;
        remain = sRemain;
    }
    const unsigned int tu = prefix;

    float z = 0.f, ssel = 0.f;
#pragma unroll
    for (int e = 0; e < 16; ++e) {
        float ex = expf(sv[e] - m);
        z += ex;
        if (mu[e] >= tu) ssel += ex;
    }
#pragma unroll
    for (int off = 32; off > 0; off >>= 1) {
        z    += __shfl_xor(z, off);
        ssel += __shfl_xor(ssel, off);
    }
    __syncthreads();
    if (lane == 0) { sRed[wid] = z; sRed[4 + wid] = ssel; }
    __syncthreads();
    const float zt = sRed[0] + sRed[1] + sRed[2] + sRed[3];
    const float st = sRed[4] + sRed[5] + sRed[6] + sRed[7];
    const float inv = 1.f / (st + 1e-6f * zt);

#pragma unroll
    for (int q = 0; q < 2; ++q) {
        unsigned int* pu = (unsigned int*)&rv[q];
#pragma unroll
        for (int dw = 0; dw < 4; ++dw) {
            int e = q * 8 + dw * 2;
            unsigned int p0 = (mu[e] >= tu) ? (unsigned int)f2h(expf(sv[e] - m) * inv) : 0u;
            unsigned int p1 = (mu[e + 1] >= tu) ? (unsigned int)f2h(expf(sv[e + 1] - m) * inv) : 0u;
            pu[dw] = p0 | (p1 << 16);
        }
    }
    row[t]       = rv[0];
    row[t + 256] = rv[1];
}

// ---------------------------------------------------------------------------
// pv (MFMA f16, split-K=16): gc_partH[b][ks][lr][i] (f16) over ks*JCH..+JCH.
// grid (qr/64, KS_PV, B)
// ---------------------------------------------------------------------------
__global__ __launch_bounds__(256) void pv_kernel(
    const unsigned short* __restrict__ SH, const unsigned short* __restrict__ gWTH,
    const int* __restrict__ cnt, unsigned short* __restrict__ gc_partH,
    int r0base, int qr)
{
    __shared__ unsigned short Pt[64][72];
    __shared__ unsigned short Gt[128][72];

    const int b = blockIdx.z;
    const int count = cnt[b];
    const int lr0 = blockIdx.x * 64;
    if (r0base + lr0 >= count) return;
    const int ks = blockIdx.y;
    const int t = threadIdx.x;
    const int w = t >> 6, lane = t & 63;
    const int lrow = lane & 15, lk = (lane >> 4) * 8;
    const int wiA = (w & 1) * 64, wrB = (w >> 1) * 32;

    f32x4 acc[4][2];
#pragma unroll
    for (int u = 0; u < 4; ++u)
#pragma unroll
        for (int v = 0; v < 2; ++v) acc[u][v] = (f32x4)(0.f);

    for (int jc = ks * JCH; jc < ks * JCH + JCH; jc += 64) {
        __syncthreads();
#pragma unroll
        for (int s = 0; s < 2; ++s) {
            int e4 = t + 256 * s;
            int r = e4 >> 3, k8 = e4 & 7;
            *(float4*)&Pt[r][k8 * 8] =
                *(const float4*)&SH[((size_t)b * qr + lr0 + r) * N_ + jc + k8 * 8];
        }
#pragma unroll
        for (int s = 0; s < 4; ++s) {
            int e4 = t + 256 * s;
            int i = e4 >> 3, k8 = e4 & 7;
            *(float4*)&Gt[i][k8 * 8] =
                *(const float4*)&gWTH[((size_t)b * IC_ + i) * N_ + jc + k8 * 8];
        }
        __syncthreads();

#pragma unroll
        for (int kstep = 0; kstep < 2; ++kstep) {
            const int kk = kstep * 32 + lk;
            f16x8 af[4], bf[2];
#pragma unroll
            for (int u = 0; u < 4; ++u)
                af[u] = *(const f16x8*)&Gt[wiA + u * 16 + lrow][kk];
#pragma unroll
            for (int v = 0; v < 2; ++v)
                bf[v] = *(const f16x8*)&Pt[wrB + v * 16 + lrow][kk];
#pragma unroll
            for (int u = 0; u < 4; ++u)
#pragma unroll
                for (int v = 0; v < 2; ++v)
                    acc[u][v] = __builtin_amdgcn_mfma_f32_16x16x32_f16(
                        af[u], bf[v], acc[u][v], 0, 0, 0);
        }
    }

    const int crow = (lane >> 4) * 4;
#pragma unroll
    for (int u = 0; u < 4; ++u) {
        const int ib = wiA + u * 16 + crow;
#pragma unroll
        for (int v = 0; v < 2; ++v) {
            const int r = lr0 + wrB + v * 16 + lrow;
            ushort4 h;
            h.x = f2h(acc[u][v][0]);
            h.y = f2h(acc[u][v][1]);
            h.z = f2h(acc[u][v][2]);
            h.w = f2h(acc[u][v][3]);
            *(ushort4*)&gc_partH[(((size_t)b * KS_PV + ks) * qr + r) * IC_ + ib] = h;
        }
    }
}

// ---------------------------------------------------------------------------
// dense scatter: for every (b,n,i) — rank<0 -> 0 (pass 0 only), else reduce
// f16 split-K partials + ReLU. grid (N*IC/256, B)
// ---------------------------------------------------------------------------
__global__ __launch_bounds__(256) void scatter_kernel(
    const unsigned short* __restrict__ gc_partH, const int* __restrict__ rank,
    float* __restrict__ gc, int r0base, int qr)
{
    const int b = blockIdx.y;
    int idx = blockIdx.x * 256 + threadIdx.x;
    int n = idx >> 7, i = idx & 127;
    int r = rank[b * N_ + n];
    if (r < 0) {
        if (r0base == 0) gc[((size_t)b * N_ + n) * IC_ + i] = 0.f;
        return;
    }
    if (r < r0base || r >= r0base + qr) return;
    const int lr = r - r0base;
    float v = 0.f;
#pragma unroll
    for (int ks = 0; ks < KS_PV; ++ks)
        v += h2f(gc_partH[(((size_t)b * KS_PV + ks) * qr + lr) * IC_ + i]);
    gc[((size_t)b * N_ + n) * IC_ + i] = fmaxf(v, 0.f);
}

// ---------------------------------------------------------------------------
// y[b,c,n] = Wout[c,:] . gc[b,n,:] + bout[c].  64c x 64n tiles.
// ---------------------------------------------------------------------------
__global__ __launch_bounds__(256) void y_kernel(
    const float* __restrict__ gc, const float* __restrict__ Wout,
    const float* __restrict__ bout, float* __restrict__ y)
{
    __shared__ float Wt[64][33];
    __shared__ float Gt[32][68];
    const int n0 = blockIdx.x * 64;
    const int c0 = blockIdx.y * 64;
    const int b  = blockIdx.z;
    const int t = threadIdx.x;
    const int tx = t & 15, ty = t >> 4;

    float acc[4][4];
#pragma unroll
    for (int u = 0; u < 4; ++u)
#pragma unroll
        for (int v = 0; v < 4; ++v) acc[u][v] = 0.f;

    for (int kc = 0; kc < IC_; kc += 32) {
        __syncthreads();
#pragma unroll
        for (int s = 0; s < 2; ++s) {
            int e4 = t + 256 * s;
            int c = e4 >> 3, k4 = e4 & 7;
            float4 ww = *(const float4*)&Wout[(size_t)(c0 + c) * IC_ + kc + k4 * 4];
            Wt[c][k4 * 4 + 0] = ww.x; Wt[c][k4 * 4 + 1] = ww.y;
            Wt[c][k4 * 4 + 2] = ww.z; Wt[c][k4 * 4 + 3] = ww.w;
        }
#pragma unroll
        for (int s = 0; s < 2; ++s) {
            int e4 = t + 256 * s;
            int nn = e4 >> 3, k4 = e4 & 7;
            float4 g = *(const float4*)&gc[((size_t)b * N_ + n0 + nn) * IC_ + kc + k4 * 4];
            Gt[k4 * 4 + 0][nn] = g.x; Gt[k4 * 4 + 1][nn] = g.y;
            Gt[k4 * 4 + 2][nn] = g.z; Gt[k4 * 4 + 3][nn] = g.w;
        }
        __syncthreads();

#pragma unroll 4
        for (int k = 0; k < 32; ++k) {
            float a[4];
#pragma unroll
            for (int u = 0; u < 4; ++u) a[u] = Wt[ty * 4 + u][k];
            const float4 g4 = *(const float4*)&Gt[k][tx * 4];
            const float gm[4] = {g4.x, g4.y, g4.z, g4.w};
#pragma unroll
            for (int u = 0; u < 4; ++u)
#pragma unroll
                for (int v = 0; v < 4; ++v)
                    acc[u][v] = fmaf(a[u], gm[v], acc[u][v]);
        }
    }

#pragma unroll
    for (int u = 0; u < 4; ++u) {
        const int c = c0 + ty * 4 + u;
        const float bo = bout[c];
        *(float4*)&y[((size_t)b * C_ + c) * N_ + n0 + tx * 4] =
            make_float4(acc[u][0] + bo, acc[u][1] + bo,
                        acc[u][2] + bo, acc[u][3] + bo);
    }
}

// ---------------------------------------------------------------------------
// BatchNorm stats per channel
// ---------------------------------------------------------------------------
__global__ __launch_bounds__(256) void bn_stats_kernel(
    const float* __restrict__ y, float* __restrict__ mean,
    float* __restrict__ rsig)
{
    __shared__ float sr[8];
    const int c = blockIdx.x, t = threadIdx.x;
    const int lane = t & 63, wid = t >> 6;
    float s = 0.f, ss = 0.f;
    for (int b = 0; b < B_; ++b) {
        const float* yr = y + ((size_t)b * C_ + c) * N_;
        for (int n = t; n < N_; n += 256) {
            float v = yr[n];
            s += v; ss = fmaf(v, v, ss);
        }
    }
#pragma unroll
    for (int off = 32; off > 0; off >>= 1) {
        s  += __shfl_xor(s, off);
        ss += __shfl_xor(ss, off);
    }
    if (lane == 0) { sr[wid] = s; sr[4 + wid] = ss; }
    __syncthreads();
    if (t == 0) {
        float st  = sr[0] + sr[1] + sr[2] + sr[3];
        float sst = sr[4] + sr[5] + sr[6] + sr[7];
        float mu  = st / (float)(B_ * N_);
        float var = sst / (float)(B_ * N_) - mu * mu;
        mean[c] = mu;
        rsig[c] = rsqrtf(var + 1e-5f);
    }
}

// ---------------------------------------------------------------------------
// out = x + gamma*(y-mean)*rsig + beta
// ---------------------------------------------------------------------------
__global__ __launch_bounds__(256) void final_kernel(
    const float* __restrict__ x, const float* __restrict__ y,
    const float* __restrict__ mean, const float* __restrict__ rsig,
    const float* __restrict__ gamma, const float* __restrict__ beta,
    float* __restrict__ out)
{
    int idx = blockIdx.x * 256 + threadIdx.x;
    if (idx >= B_ * C_ * N_) return;
    int c = (idx >> 12) & (C_ - 1);
    out[idx] = x[idx] + fmaf(gamma[c], (y[idx] - mean[c]) * rsig[c], beta[c]);
}

extern "C" void kernel_launch(void* const* d_in, const int* in_sizes, int n_in,
                              void* d_out, int out_size, void* d_ws, size_t ws_size,
                              hipStream_t stream)
{
    const float* x     = (const float*)d_in[0];
    const float* hard  = (const float*)d_in[1];
    const float* Wg    = (const float*)d_in[2];
    const float* bg    = (const float*)d_in[3];
    const float* Wth   = (const float*)d_in[4];
    const float* bth   = (const float*)d_in[5];
    const float* Wph   = (const float*)d_in[6];
    const float* bph   = (const float*)d_in[7];
    const float* Wgcn  = (const float*)d_in[8];
    const float* Wout  = (const float*)d_in[9];
    const float* bout  = (const float*)d_in[10];
    const float* gamma = (const float*)d_in[11];
    const float* beta  = (const float*)d_in[12];
    float* out = (float*)d_out;
    float* ws  = (float*)d_ws;

    float* gc    = ws + OFF_GC;
    float* y     = ws + OFF_Y;
    float* mean  = ws + OFF_MEAN;
    float* rsig  = ws + OFF_RSIG;
    int*   cnt   = (int*)(ws + OFF_CNT);
    int*   list  = (int*)(ws + OFF_LIST);
    int*   rank  = (int*)(ws + OFF_RANK);
    unsigned short* thetaH = (unsigned short*)(ws + OFF_THB);
    unsigned short* phiH   = (unsigned short*)(ws + OFF_PHB);
    unsigned short* gWTH   = (unsigned short*)(ws + OFF_GWT);
    unsigned short* xTH    = (unsigned short*)(ws + OFF_XTH);
    unsigned short* WallH  = (unsigned short*)(ws + OFF_WALL);
    float* ball  = ws + OFF_BALL;
    unsigned short* SH = (unsigned short*)(ws + OFF_S);

    // runtime-adaptive row-block; partials f16.
    // SH = qr*4096 floats, gc_part = qr*2048 floats -> qr*6144 total
    const size_t wsf = ws_size / sizeof(float);
    int qr;
    unsigned short* gc_partH;
    if (wsf >= OFF_S + (size_t)4096 * 6144) {            // >= 124 MB total
        qr = 4096; gc_partH = (unsigned short*)(ws + OFF_S + (size_t)4096 * 4096);
    } else if (wsf >= OFF_S + (size_t)2048 * 6144) {
        qr = 2048; gc_partH = (unsigned short*)(ws + OFF_S + (size_t)2048 * 4096);
    } else {
        qr = 512; gc_partH = (unsigned short*)out;   // 4.2 MB < 8 MB d_out;
                                                     // overwritten by final
    }

    prep_kernel<<<dim3(898), 256, 0, stream>>>(
        x, xTH, Wth, bth, Wg, bg, Wgcn, Wph, bph, WallH, ball,
        hard, cnt, list, rank);
    proj_kernel<<<dim3(N_ / 128, 3, B_), 256, 0, stream>>>(
        xTH, WallH, ball, thetaH, gWTH, phiH);

    for (int r0 = 0; r0 < N_; r0 += qr) {
        score_kernel<<<dim3(N_ / 128, qr / 128, B_), 256, 0, stream>>>(
            thetaH, phiH, cnt, list, SH, r0, qr);
        select_kernel<<<dim3(qr, B_), 256, 0, stream>>>(SH, cnt, r0, qr);
        pv_kernel<<<dim3(qr / 64, KS_PV, B_), 256, 0, stream>>>(
            SH, gWTH, cnt, gc_partH, r0, qr);
        scatter_kernel<<<dim3(N_ * IC_ / 256, B_), 256, 0, stream>>>(
            gc_partH, rank, gc, r0, qr);
    }

    y_kernel<<<dim3(N_ / 64, C_ / 64, B_), 256, 0, stream>>>(gc, Wout, bout, y);
    bn_stats_kernel<<<dim3(C_), 256, 0, stream>>>(y, mean, rsig);
    final_kernel<<<dim3(B_ * C_ * N_ / 256), 256, 0, stream>>>(
        x, y, mean, rsig, gamma, beta, out);
}

// Round 17
// 129.000 us; speedup vs baseline: 2.3068x; 1.0294x over previous
//
#include <hip/hip_runtime.h>

#define B_ 2
#define C_ 256
#define IC_ 128
#define N_ 4096
#define KSEL 2048
#define KS_PV 8

// fixed workspace offsets (floats); SH + gc_part sized at runtime
#define OFF_GC    0u          // gc f32 [B][N][IC]
#define OFF_Y     1048576u    // y  f32 [B][C][N]
#define OFF_MEAN  3145728u
#define OFF_RSIG  3145984u
#define OFF_CNT   3146240u
#define OFF_LIST  3146304u    // int[B*N]
#define OFF_RANK  3154496u    // int[B*N]
#define OFF_THB   3162688u    // theta f16 [B][N][IC]
#define OFF_PHB   3686976u    // phi   f16 [B][N][IC]
#define OFF_GWT   4211264u    // gW^T  f16 [B][IC][N]
#define OFF_XTH   4735552u    // x^T   f16 [B][N][C]
#define OFF_WALL  5784128u    // {Wth,Weff,Wph} f16 [384][256]
#define OFF_BALL  5833280u    // f32 [384]
#define OFF_S     5833664u    // SH f16 [B][qr][N]; then gc_part f16

typedef __attribute__((ext_vector_type(8))) _Float16 f16x8;
typedef __attribute__((ext_vector_type(4))) float f32x4;

__device__ __forceinline__ unsigned short f2h(float f) {
    union { _Float16 h; unsigned short u; } cv;
    cv.h = (_Float16)f;
    return cv.u;
}
__device__ __forceinline__ float h2f(unsigned short u) {
    union { unsigned short u; _Float16 h; } cv;
    cv.u = u;
    return (float)cv.h;
}

// ---------------------------------------------------------------------------
// prep: fused {xT transpose (blocks 0..511), W pack + Weff (512..895),
//              hard-row compaction + rank map (896..897)}
// ---------------------------------------------------------------------------
__global__ __launch_bounds__(256) void prep_kernel(
    const float* __restrict__ x, unsigned short* __restrict__ xTH,
    const float* __restrict__ Wth, const float* __restrict__ bth,
    const float* __restrict__ Wg,  const float* __restrict__ bg,
    const float* __restrict__ Wgcn,
    const float* __restrict__ Wph, const float* __restrict__ bph,
    unsigned short* __restrict__ WallH, float* __restrict__ ball,
    const float* __restrict__ hard_map, int* __restrict__ cnt,
    int* __restrict__ list, int* __restrict__ rank)
{
    __shared__ float Xs[64][65];
    __shared__ int wsum[4];
    const int bid = blockIdx.x;
    const int t = threadIdx.x;

    if (bid < 512) {
        // ---- xT: x [b][c][n] f32 -> xTH [b][n][c] f16, 64x64 tile ----
        const int n0 = (bid & 63) * 64;
        const int c0 = ((bid >> 6) & 3) * 64;
        const int b  = bid >> 8;
#pragma unroll
        for (int s = 0; s < 4; ++s) {
            int e4 = t + 256 * s;
            int cc = e4 >> 4, c4 = e4 & 15;
            float4 v = *(const float4*)&x[((size_t)b * C_ + c0 + cc) * N_ + n0 + c4 * 4];
            Xs[cc][c4 * 4 + 0] = v.x; Xs[cc][c4 * 4 + 1] = v.y;
            Xs[cc][c4 * 4 + 2] = v.z; Xs[cc][c4 * 4 + 3] = v.w;
        }
        __syncthreads();
#pragma unroll
        for (int s = 0; s < 4; ++s) {
            int e = t + 256 * s;
            int nn = e >> 4, c4 = e & 15;
            ushort4 h;
            h.x = f2h(Xs[c4 * 4 + 0][nn]);
            h.y = f2h(Xs[c4 * 4 + 1][nn]);
            h.z = f2h(Xs[c4 * 4 + 2][nn]);
            h.w = f2h(Xs[c4 * 4 + 3][nn]);
            *(ushort4*)&xTH[((size_t)b * N_ + n0 + nn) * C_ + c0 + c4 * 4] = h;
        }
    } else if (bid < 896) {
        // ---- W pack: {Wth, Wgcn^T.Wg, Wph} -> WallH [384][256] + ball ----
        const int o = bid - 512;
        const int c = t;
        const int oo = o & 127;
        float wv, bv;
        if (o < 128) {
            wv = Wth[oo * C_ + c];
            bv = bth[oo];
        } else if (o < 256) {
            float acc = 0.f;
            for (int i = 0; i < IC_; ++i)
                acc = fmaf(Wgcn[i * IC_ + oo], Wg[i * C_ + c], acc);
            wv = acc;
            float bacc = 0.f;
            for (int i = 0; i < IC_; ++i)
                bacc = fmaf(Wgcn[i * IC_ + oo], bg[i], bacc);
            bv = bacc;
        } else {
            wv = Wph[oo * C_ + c];
            bv = bph[oo];
        }
        WallH[o * C_ + c] = f2h(wv);
        if (c == 0) ball[o] = bv;
    } else {
        // ---- compaction: 256 threads x 16 elements, atomic-free scan ----
        const int b = bid - 896;
        const int lane = t & 63, wid = t >> 6;
        const float* hm = hard_map + (size_t)b * N_;
        int flags[16];
        int c = 0;
#pragma unroll
        for (int q = 0; q < 4; ++q) {
            float4 v = *(const float4*)&hm[t * 16 + q * 4];
            flags[q * 4 + 0] = v.x > 0.5f;
            flags[q * 4 + 1] = v.y > 0.5f;
            flags[q * 4 + 2] = v.z > 0.5f;
            flags[q * 4 + 3] = v.w > 0.5f;
            c += flags[q * 4] + flags[q * 4 + 1] + flags[q * 4 + 2] + flags[q * 4 + 3];
        }
        int xv = c;
#pragma unroll
        for (int off = 1; off < 64; off <<= 1) {
            int y = __shfl_up(xv, off);
            if (lane >= off) xv += y;
        }
        if (lane == 63) wsum[wid] = xv;
        __syncthreads();
        int base = 0;
        for (int ww = 0; ww < wid; ++ww) base += wsum[ww];
        int pos = base + xv - c;
        int* lst = list + b * N_;
        int* rnk = rank + b * N_;
#pragma unroll
        for (int e = 0; e < 16; ++e) {
            int n = t * 16 + e;
            if (flags[e]) { lst[pos] = n; rnk[n] = pos; ++pos; }
            else rnk[n] = -1;
        }
        if (t == 0) {
            int tot = 0;
#pragma unroll
            for (int ww = 0; ww < 4; ++ww) tot += wsum[ww];
            cnt[b] = tot;
        }
    }
}

// ---------------------------------------------------------------------------
// proj (MFMA f16): out[o][n] = WallH[pj-chunk] . xT, K=256.
// grid (N/128, 3, B)
// ---------------------------------------------------------------------------
__global__ __launch_bounds__(256) void proj_kernel(
    const unsigned short* __restrict__ xTH,
    const unsigned short* __restrict__ WallH, const float* __restrict__ ball,
    unsigned short* __restrict__ thetaH, unsigned short* __restrict__ gWTH,
    unsigned short* __restrict__ phiH)
{
    __shared__ unsigned short Xt[128][72];
    __shared__ unsigned short Wt[128][72];
    const int n0 = blockIdx.x * 128;
    const int pj = blockIdx.y;
    const int b  = blockIdx.z;
    const int t = threadIdx.x, w = t >> 6, lane = t & 63;
    const int lrow = lane & 15, lk = (lane >> 4) * 8;
    const int wA = (w >> 1) * 64, wB = (w & 1) * 64;

    f32x4 acc[4][4];
#pragma unroll
    for (int u = 0; u < 4; ++u)
#pragma unroll
        for (int v = 0; v < 4; ++v) acc[u][v] = (f32x4)(0.f);

    for (int kc = 0; kc < C_; kc += 64) {
        __syncthreads();
#pragma unroll
        for (int s = 0; s < 4; ++s) {
            int e4 = t + 256 * s;
            int r = e4 >> 3, k8 = e4 & 7;
            *(float4*)&Xt[r][k8 * 8] =
                *(const float4*)&xTH[((size_t)b * N_ + n0 + r) * C_ + kc + k8 * 8];
        }
#pragma unroll
        for (int s = 0; s < 4; ++s) {
            int e4 = t + 256 * s;
            int r = e4 >> 3, k8 = e4 & 7;
            *(float4*)&Wt[r][k8 * 8] =
                *(const float4*)&WallH[(size_t)(pj * 128 + r) * C_ + kc + k8 * 8];
        }
        __syncthreads();

#pragma unroll
        for (int kstep = 0; kstep < 2; ++kstep) {
            const int kk = kstep * 32 + lk;
            f16x8 af[4], bf[4];
            if (pj != 1) {
#pragma unroll
                for (int u = 0; u < 4; ++u)
                    af[u] = *(const f16x8*)&Wt[wA + u * 16 + lrow][kk];
#pragma unroll
                for (int v = 0; v < 4; ++v)
                    bf[v] = *(const f16x8*)&Xt[wB + v * 16 + lrow][kk];
            } else {
#pragma unroll
                for (int u = 0; u < 4; ++u)
                    af[u] = *(const f16x8*)&Xt[wA + u * 16 + lrow][kk];
#pragma unroll
                for (int v = 0; v < 4; ++v)
                    bf[v] = *(const f16x8*)&Wt[wB + v * 16 + lrow][kk];
            }
#pragma unroll
            for (int u = 0; u < 4; ++u)
#pragma unroll
                for (int v = 0; v < 4; ++v)
                    acc[u][v] = __builtin_amdgcn_mfma_f32_16x16x32_f16(
                        af[u], bf[v], acc[u][v], 0, 0, 0);
        }
    }

    const int crow = (lane >> 4) * 4;
    if (pj != 1) {
        unsigned short* dst = (pj == 0) ? thetaH : phiH;
        const int bb2 = (pj == 0) ? 0 : 256;
#pragma unroll
        for (int u = 0; u < 4; ++u) {
            const int ob = wA + u * 16 + crow;
            float b0 = ball[bb2 + ob + 0], b1 = ball[bb2 + ob + 1];
            float b2 = ball[bb2 + ob + 2], b3 = ball[bb2 + ob + 3];
#pragma unroll
            for (int v = 0; v < 4; ++v) {
                const int n = n0 + wB + v * 16 + lrow;
                ushort4 h;
                h.x = f2h(acc[u][v][0] + b0);
                h.y = f2h(acc[u][v][1] + b1);
                h.z = f2h(acc[u][v][2] + b2);
                h.w = f2h(acc[u][v][3] + b3);
                *(ushort4*)&dst[((size_t)b * N_ + n) * IC_ + ob] = h;
            }
        }
    } else {
#pragma unroll
        for (int v = 0; v < 4; ++v) {
            const int o = wB + v * 16 + lrow;
            const float bo = ball[128 + o];
#pragma unroll
            for (int u = 0; u < 4; ++u) {
                const int nb = n0 + wA + u * 16 + crow;
                ushort4 h;
                h.x = f2h(acc[u][v][0] + bo);
                h.y = f2h(acc[u][v][1] + bo);
                h.z = f2h(acc[u][v][2] + bo);
                h.w = f2h(acc[u][v][3] + bo);
                *(ushort4*)&gWTH[((size_t)b * IC_ + o) * N_ + nb] = h;
            }
        }
    }
}

// ---------------------------------------------------------------------------
// score (MFMA f16): SH[b][lr][m] = theta_row(lr) . phi[:,m], f16 out.
// grid (N/128, qr/128, B)
// ---------------------------------------------------------------------------
__global__ __launch_bounds__(256) void score_kernel(
    const unsigned short* __restrict__ thetaH,
    const unsigned short* __restrict__ phiH,
    const int* __restrict__ cnt, const int* __restrict__ list,
    unsigned short* __restrict__ SH, int r0base, int qr)
{
    __shared__ unsigned short Th[128][136];
    __shared__ unsigned short Ph[128][136];
    __shared__ int sIdx[128];

    const int b = blockIdx.z;
    const int count = cnt[b];
    const int lr0 = blockIdx.y * 128;
    if (r0base + lr0 >= count) return;
    const int m0 = blockIdx.x * 128;
    const int t = threadIdx.x;
    const int w = t >> 6, lane = t & 63;

    if (t < 128) {
        int gr = r0base + lr0 + t;
        sIdx[t] = (gr < count) ? list[b * N_ + gr] : -1;
    }
    __syncthreads();

#pragma unroll
    for (int s = 0; s < 8; ++s) {
        int e4 = t + 256 * s;
        int r = e4 >> 4, k4 = e4 & 15;
        int gr = sIdx[r];
        float4 v = make_float4(0.f, 0.f, 0.f, 0.f);
        if (gr >= 0)
            v = *(const float4*)&thetaH[((size_t)b * N_ + gr) * IC_ + k4 * 8];
        *(float4*)&Th[r][k4 * 8] = v;
    }
#pragma unroll
    for (int s = 0; s < 8; ++s) {
        int e4 = t + 256 * s;
        int r = e4 >> 4, k4 = e4 & 15;
        *(float4*)&Ph[r][k4 * 8] =
            *(const float4*)&phiH[((size_t)b * N_ + m0 + r) * IC_ + k4 * 8];
    }
    __syncthreads();

    const int wm = (w >> 1) * 64, wr = (w & 1) * 64;
    const int lrow = lane & 15, lk = (lane >> 4) * 8;

    f32x4 acc[4][4];
#pragma unroll
    for (int u = 0; u < 4; ++u)
#pragma unroll
        for (int v = 0; v < 4; ++v) acc[u][v] = (f32x4)(0.f);

#pragma unroll
    for (int ks = 0; ks < 4; ++ks) {
        const int kk = ks * 32 + lk;
        f16x8 af[4], bf[4];
#pragma unroll
        for (int u = 0; u < 4; ++u)
            af[u] = *(const f16x8*)&Ph[wm + u * 16 + lrow][kk];
#pragma unroll
        for (int v = 0; v < 4; ++v)
            bf[v] = *(const f16x8*)&Th[wr + v * 16 + lrow][kk];
#pragma unroll
        for (int u = 0; u < 4; ++u)
#pragma unroll
            for (int v = 0; v < 4; ++v)
                acc[u][v] = __builtin_amdgcn_mfma_f32_16x16x32_f16(
                    af[u], bf[v], acc[u][v], 0, 0, 0);
    }

    const int crow = (lane >> 4) * 4;
#pragma unroll
    for (int u = 0; u < 4; ++u) {
        const int mb = m0 + wm + u * 16 + crow;
#pragma unroll
        for (int v = 0; v < 4; ++v) {
            const int r = lr0 + wr + v * 16 + lrow;
            ushort4 h;
            h.x = f2h(acc[u][v][0]);
            h.y = f2h(acc[u][v][1]);
            h.z = f2h(acc[u][v][2]);
            h.w = f2h(acc[u][v][3]);
            *(ushort4*)&SH[((size_t)b * qr + r) * N_ + mb] = h;
        }
    }
}

// ---------------------------------------------------------------------------
// select: exact kth-largest radix select (2x8-bit passes on monotone u16)
// + softmax; writes P f16 in place. grid (qr, B)
// ---------------------------------------------------------------------------
__global__ __launch_bounds__(256) void select_kernel(
    unsigned short* __restrict__ SH, const int* __restrict__ cnt,
    int r0base, int qr)
{
    __shared__ unsigned int sHist[4][256];
    __shared__ unsigned int sWsum[4];
    __shared__ float sRed[8];
    __shared__ unsigned int sPrefix, sRemain;

    const int b = blockIdx.y;
    const int lr = blockIdx.x;
    if (r0base + lr >= cnt[b]) return;
    const int t = threadIdx.x, lane = t & 63, wid = t >> 6;

    uint4* row = (uint4*)(SH + ((size_t)b * qr + lr) * N_);
    uint4 rv[2];
    rv[0] = row[t];
    rv[1] = row[t + 256];

    float sv[16];
    unsigned int mu[16];
#pragma unroll
    for (int q = 0; q < 2; ++q) {
        const unsigned int* pu = (const unsigned int*)&rv[q];
#pragma unroll
        for (int dw = 0; dw < 4; ++dw) {
            unsigned int u = pu[dw];
            unsigned short h0 = (unsigned short)(u & 0xffffu);
            unsigned short h1 = (unsigned short)(u >> 16);
            int e = q * 8 + dw * 2;
            sv[e]     = h2f(h0);
            sv[e + 1] = h2f(h1);
            mu[e]     = (h0 & 0x8000u) ? (unsigned int)((~h0) & 0xffffu)
                                       : (unsigned int)(h0 | 0x8000u);
            mu[e + 1] = (h1 & 0x8000u) ? (unsigned int)((~h1) & 0xffffu)
                                       : (unsigned int)(h1 | 0x8000u);
        }
    }

    float m = -3.4e38f;
#pragma unroll
    for (int e = 0; e < 16; ++e) m = fmaxf(m, sv[e]);
#pragma unroll
    for (int off = 32; off > 0; off >>= 1) m = fmaxf(m, __shfl_xor(m, off));
    if (lane == 0) sRed[wid] = m;
    __syncthreads();
    m = fmaxf(fmaxf(sRed[0], sRed[1]), fmaxf(sRed[2], sRed[3]));

    unsigned int prefix = 0u;
    unsigned int remain = KSEL;
    for (int d = 1; d >= 0; --d) {
        __syncthreads();
#pragma unroll
        for (int ww = 0; ww < 4; ++ww) sHist[ww][t] = 0u;
        __syncthreads();
#pragma unroll
        for (int e = 0; e < 16; ++e) {
            if ((mu[e] >> (8 * (d + 1))) == prefix)
                atomicAdd(&sHist[wid][(mu[e] >> (8 * d)) & 255u], 1u);
        }
        __syncthreads();
        unsigned int x = sHist[0][t] + sHist[1][t] + sHist[2][t] + sHist[3][t];
        unsigned int own = x;
#pragma unroll
        for (int off = 1; off < 64; off <<= 1) {
            unsigned int y = __shfl_down(x, off);
            if (lane + off < 64) x += y;
        }
        if (lane == 0) sWsum[wid] = x;
        __syncthreads();
        for (int ww = wid + 1; ww < 4; ++ww) x += sWsum[ww];
        unsigned int nxt = x - own;
        if (x >= remain && nxt < remain) {
            sPrefix = (prefix << 8) | (unsigned int)t;
            sRemain = remain - nxt;
        }
        __syncthreads();
        prefix = sPrefix;
        remain = sRemain;
    }
    const unsigned int tu = prefix;

    float z = 0.f, ssel = 0.f;
#pragma unroll
    for (int e = 0; e < 16; ++e) {
        float ex = expf(sv[e] - m);
        z += ex;
        if (mu[e] >= tu) ssel += ex;
    }
#pragma unroll
    for (int off = 32; off > 0; off >>= 1) {
        z    += __shfl_xor(z, off);
        ssel += __shfl_xor(ssel, off);
    }
    __syncthreads();
    if (lane == 0) { sRed[wid] = z; sRed[4 + wid] = ssel; }
    __syncthreads();
    const float zt = sRed[0] + sRed[1] + sRed[2] + sRed[3];
    const float st = sRed[4] + sRed[5] + sRed[6] + sRed[7];
    const float inv = 1.f / (st + 1e-6f * zt);

#pragma unroll
    for (int q = 0; q < 2; ++q) {
        unsigned int* pu = (unsigned int*)&rv[q];
#pragma unroll
        for (int dw = 0; dw < 4; ++dw) {
            int e = q * 8 + dw * 2;
            unsigned int p0 = (mu[e] >= tu) ? (unsigned int)f2h(expf(sv[e] - m) * inv) : 0u;
            unsigned int p1 = (mu[e + 1] >= tu) ? (unsigned int)f2h(expf(sv[e + 1] - m) * inv) : 0u;
            pu[dw] = p0 | (p1 << 16);
        }
    }
    row[t]       = rv[0];
    row[t + 256] = rv[1];
}

// ---------------------------------------------------------------------------
// pv (MFMA f16, split-K=8): gc_partH[b][ks][lr][i] (f16) over ks*512..+512.
// grid (qr/64, 8, B)
// ---------------------------------------------------------------------------
__global__ __launch_bounds__(256) void pv_kernel(
    const unsigned short* __restrict__ SH, const unsigned short* __restrict__ gWTH,
    const int* __restrict__ cnt, unsigned short* __restrict__ gc_partH,
    int r0base, int qr)
{
    __shared__ unsigned short Pt[64][72];
    __shared__ unsigned short Gt[128][72];

    const int b = blockIdx.z;
    const int count = cnt[b];
    const int lr0 = blockIdx.x * 64;
    if (r0base + lr0 >= count) return;
    const int ks = blockIdx.y;
    const int t = threadIdx.x;
    const int w = t >> 6, lane = t & 63;
    const int lrow = lane & 15, lk = (lane >> 4) * 8;
    const int wiA = (w & 1) * 64, wrB = (w >> 1) * 32;

    f32x4 acc[4][2];
#pragma unroll
    for (int u = 0; u < 4; ++u)
#pragma unroll
        for (int v = 0; v < 2; ++v) acc[u][v] = (f32x4)(0.f);

    for (int jc = ks * 512; jc < ks * 512 + 512; jc += 64) {
        __syncthreads();
#pragma unroll
        for (int s = 0; s < 2; ++s) {
            int e4 = t + 256 * s;
            int r = e4 >> 3, k8 = e4 & 7;
            *(float4*)&Pt[r][k8 * 8] =
                *(const float4*)&SH[((size_t)b * qr + lr0 + r) * N_ + jc + k8 * 8];
        }
#pragma unroll
        for (int s = 0; s < 4; ++s) {
            int e4 = t + 256 * s;
            int i = e4 >> 3, k8 = e4 & 7;
            *(float4*)&Gt[i][k8 * 8] =
                *(const float4*)&gWTH[((size_t)b * IC_ + i) * N_ + jc + k8 * 8];
        }
        __syncthreads();

#pragma unroll
        for (int kstep = 0; kstep < 2; ++kstep) {
            const int kk = kstep * 32 + lk;
            f16x8 af[4], bf[2];
#pragma unroll
            for (int u = 0; u < 4; ++u)
                af[u] = *(const f16x8*)&Gt[wiA + u * 16 + lrow][kk];
#pragma unroll
            for (int v = 0; v < 2; ++v)
                bf[v] = *(const f16x8*)&Pt[wrB + v * 16 + lrow][kk];
#pragma unroll
            for (int u = 0; u < 4; ++u)
#pragma unroll
                for (int v = 0; v < 2; ++v)
                    acc[u][v] = __builtin_amdgcn_mfma_f32_16x16x32_f16(
                        af[u], bf[v], acc[u][v], 0, 0, 0);
        }
    }

    const int crow = (lane >> 4) * 4;
#pragma unroll
    for (int u = 0; u < 4; ++u) {
        const int ib = wiA + u * 16 + crow;
#pragma unroll
        for (int v = 0; v < 2; ++v) {
            const int r = lr0 + wrB + v * 16 + lrow;
            ushort4 h;
            h.x = f2h(acc[u][v][0]);
            h.y = f2h(acc[u][v][1]);
            h.z = f2h(acc[u][v][2]);
            h.w = f2h(acc[u][v][3]);
            *(ushort4*)&gc_partH[(((size_t)b * KS_PV + ks) * qr + r) * IC_ + ib] = h;
        }
    }
}

// ---------------------------------------------------------------------------
// dense scatter: for every (b,n,i) — rank<0 -> 0 (pass 0 only), else reduce
// f16 split-K partials + ReLU. grid (N*IC/256, B)
// ---------------------------------------------------------------------------
__global__ __launch_bounds__(256) void scatter_kernel(
    const unsigned short* __restrict__ gc_partH, const int* __restrict__ rank,
    float* __restrict__ gc, int r0base, int qr)
{
    const int b = blockIdx.y;
    int idx = blockIdx.x * 256 + threadIdx.x;
    int n = idx >> 7, i = idx & 127;
    int r = rank[b * N_ + n];
    if (r < 0) {
        if (r0base == 0) gc[((size_t)b * N_ + n) * IC_ + i] = 0.f;
        return;
    }
    if (r < r0base || r >= r0base + qr) return;
    const int lr = r - r0base;
    float v = 0.f;
#pragma unroll
    for (int ks = 0; ks < KS_PV; ++ks)
        v += h2f(gc_partH[(((size_t)b * KS_PV + ks) * qr + lr) * IC_ + i]);
    gc[((size_t)b * N_ + n) * IC_ + i] = fmaxf(v, 0.f);
}

// ---------------------------------------------------------------------------
// y[b,c,n] = Wout[c,:] . gc[b,n,:] + bout[c].  64c x 64n tiles.
// ---------------------------------------------------------------------------
__global__ __launch_bounds__(256) void y_kernel(
    const float* __restrict__ gc, const float* __restrict__ Wout,
    const float* __restrict__ bout, float* __restrict__ y)
{
    __shared__ float Wt[64][33];
    __shared__ float Gt[32][68];
    const int n0 = blockIdx.x * 64;
    const int c0 = blockIdx.y * 64;
    const int b  = blockIdx.z;
    const int t = threadIdx.x;
    const int tx = t & 15, ty = t >> 4;

    float acc[4][4];
#pragma unroll
    for (int u = 0; u < 4; ++u)
#pragma unroll
        for (int v = 0; v < 4; ++v) acc[u][v] = 0.f;

    for (int kc = 0; kc < IC_; kc += 32) {
        __syncthreads();
#pragma unroll
        for (int s = 0; s < 2; ++s) {
            int e4 = t + 256 * s;
            int c = e4 >> 3, k4 = e4 & 7;
            float4 ww = *(const float4*)&Wout[(size_t)(c0 + c) * IC_ + kc + k4 * 4];
            Wt[c][k4 * 4 + 0] = ww.x; Wt[c][k4 * 4 + 1] = ww.y;
            Wt[c][k4 * 4 + 2] = ww.z; Wt[c][k4 * 4 + 3] = ww.w;
        }
#pragma unroll
        for (int s = 0; s < 2; ++s) {
            int e4 = t + 256 * s;
            int nn = e4 >> 3, k4 = e4 & 7;
            float4 g = *(const float4*)&gc[((size_t)b * N_ + n0 + nn) * IC_ + kc + k4 * 4];
            Gt[k4 * 4 + 0][nn] = g.x; Gt[k4 * 4 + 1][nn] = g.y;
            Gt[k4 * 4 + 2][nn] = g.z; Gt[k4 * 4 + 3][nn] = g.w;
        }
        __syncthreads();

#pragma unroll 4
        for (int k = 0; k < 32; ++k) {
            float a[4];
#pragma unroll
            for (int u = 0; u < 4; ++u) a[u] = Wt[ty * 4 + u][k];
            const float4 g4 = *(const float4*)&Gt[k][tx * 4];
            const float gm[4] = {g4.x, g4.y, g4.z, g4.w};
#pragma unroll
            for (int u = 0; u < 4; ++u)
#pragma unroll
                for (int v = 0; v < 4; ++v)
                    acc[u][v] = fmaf(a[u], gm[v], acc[u][v]);
        }
    }

#pragma unroll
    for (int u = 0; u < 4; ++u) {
        const int c = c0 + ty * 4 + u;
        const float bo = bout[c];
        *(float4*)&y[((size_t)b * C_ + c) * N_ + n0 + tx * 4] =
            make_float4(acc[u][0] + bo, acc[u][1] + bo,
                        acc[u][2] + bo, acc[u][3] + bo);
    }
}

// ---------------------------------------------------------------------------
// BatchNorm stats per channel
// ---------------------------------------------------------------------------
__global__ __launch_bounds__(256) void bn_stats_kernel(
    const float* __restrict__ y, float* __restrict__ mean,
    float* __restrict__ rsig)
{
    __shared__ float sr[8];
    const int c = blockIdx.x, t = threadIdx.x;
    const int lane = t & 63, wid = t >> 6;
    float s = 0.f, ss = 0.f;
    for (int b = 0; b < B_; ++b) {
        const float* yr = y + ((size_t)b * C_ + c) * N_;
        for (int n = t; n < N_; n += 256) {
            float v = yr[n];
            s += v; ss = fmaf(v, v, ss);
        }
    }
#pragma unroll
    for (int off = 32; off > 0; off >>= 1) {
        s  += __shfl_xor(s, off);
        ss += __shfl_xor(ss, off);
    }
    if (lane == 0) { sr[wid] = s; sr[4 + wid] = ss; }
    __syncthreads();
    if (t == 0) {
        float st  = sr[0] + sr[1] + sr[2] + sr[3];
        float sst = sr[4] + sr[5] + sr[6] + sr[7];
        float mu  = st / (float)(B_ * N_);
        float var = sst / (float)(B_ * N_) - mu * mu;
        mean[c] = mu;
        rsig[c] = rsqrtf(var + 1e-5f);
    }
}

// ---------------------------------------------------------------------------
// out = x + gamma*(y-mean)*rsig + beta
// ---------------------------------------------------------------------------
__global__ __launch_bounds__(256) void final_kernel(
    const float* __restrict__ x, const float* __restrict__ y,
    const float* __restrict__ mean, const float* __restrict__ rsig,
    const float* __restrict__ gamma, const float* __restrict__ beta,
    float* __restrict__ out)
{
    int idx = blockIdx.x * 256 + threadIdx.x;
    if (idx >= B_ * C_ * N_) return;
    int c = (idx >> 12) & (C_ - 1);
    out[idx] = x[idx] + fmaf(gamma[c], (y[idx] - mean[c]) * rsig[c], beta[c]);
}

extern "C" void kernel_launch(void* const* d_in, const int* in_sizes, int n_in,
                              void* d_out, int out_size, void* d_ws, size_t ws_size,
                              hipStream_t stream)
{
    const float* x     = (const float*)d_in[0];
    const float* hard  = (const float*)d_in[1];
    const float* Wg    = (const float*)d_in[2];
    const float* bg    = (const float*)d_in[3];
    const float* Wth   = (const float*)d_in[4];
    const float* bth   = (const float*)d_in[5];
    const float* Wph   = (const float*)d_in[6];
    const float* bph   = (const float*)d_in[7];
    const float* Wgcn  = (const float*)d_in[8];
    const float* Wout  = (const float*)d_in[9];
    const float* bout  = (const float*)d_in[10];
    const float* gamma = (const float*)d_in[11];
    const float* beta  = (const float*)d_in[12];
    float* out = (float*)d_out;
    float* ws  = (float*)d_ws;

    float* gc    = ws + OFF_GC;
    float* y     = ws + OFF_Y;
    float* mean  = ws + OFF_MEAN;
    float* rsig  = ws + OFF_RSIG;
    int*   cnt   = (int*)(ws + OFF_CNT);
    int*   list  = (int*)(ws + OFF_LIST);
    int*   rank  = (int*)(ws + OFF_RANK);
    unsigned short* thetaH = (unsigned short*)(ws + OFF_THB);
    unsigned short* phiH   = (unsigned short*)(ws + OFF_PHB);
    unsigned short* gWTH   = (unsigned short*)(ws + OFF_GWT);
    unsigned short* xTH    = (unsigned short*)(ws + OFF_XTH);
    unsigned short* WallH  = (unsigned short*)(ws + OFF_WALL);
    float* ball  = ws + OFF_BALL;
    unsigned short* SH = (unsigned short*)(ws + OFF_S);

    // runtime-adaptive row-block; partials f16.
    // SH = qr*2048 floats/batch x B, gc_part = qr*1024 floats/batch x B
    const size_t wsf = ws_size / sizeof(float);
    int qr;
    unsigned short* gc_partH;
    if (wsf >= OFF_S + (size_t)4096 * 6144) {            // >= 124 MB total
        qr = 4096; gc_partH = (unsigned short*)(ws + OFF_S + (size_t)4096 * 4096);
    } else if (wsf >= OFF_S + (size_t)2048 * 6144) {
        qr = 2048; gc_partH = (unsigned short*)(ws + OFF_S + (size_t)2048 * 4096);
    } else {
        qr = 1024; gc_partH = (unsigned short*)out;  // 4.2 MB < 8 MB d_out;
                                                     // overwritten by final
    }

    prep_kernel<<<dim3(898), 256, 0, stream>>>(
        x, xTH, Wth, bth, Wg, bg, Wgcn, Wph, bph, WallH, ball,
        hard, cnt, list, rank);
    proj_kernel<<<dim3(N_ / 128, 3, B_), 256, 0, stream>>>(
        xTH, WallH, ball, thetaH, gWTH, phiH);

    for (int r0 = 0; r0 < N_; r0 += qr) {
        score_kernel<<<dim3(N_ / 128, qr / 128, B_), 256, 0, stream>>>(
            thetaH, phiH, cnt, list, SH, r0, qr);
        select_kernel<<<dim3(qr, B_), 256, 0, stream>>>(SH, cnt, r0, qr);
        pv_kernel<<<dim3(qr / 64, KS_PV, B_), 256, 0, stream>>>(
            SH, gWTH, cnt, gc_partH, r0, qr);
        scatter_kernel<<<dim3(N_ * IC_ / 256, B_), 256, 0, stream>>>(
            gc_partH, rank, gc, r0, qr);
    }

    y_kernel<<<dim3(N_ / 64, C_ / 64, B_), 256, 0, stream>>>(gc, Wout, bout, y);
    bn_stats_kernel<<<dim3(C_), 256, 0, stream>>>(y, mean, rsig);
    final_kernel<<<dim3(B_ * C_ * N_ / 256), 256, 0, stream>>>(
        x, y, mean, rsig, gamma, beta, out);
}